// Round 20
// baseline (553.659 us; speedup 1.0000x reference)
//
#include <hip/hip_runtime.h>
#include <math.h>

// ---------------------------------------------------------------------------
// Model constants
// ---------------------------------------------------------------------------
namespace {
constexpr int B_ = 4, T_ = 12, N_ = 2000, D_ = 16, FF_ = 64, E_ = 4, L_ = 2;
constexpr int EA_ = 3000, H_ = 3, HD_ = EA_ / H_;   // 1000
constexpr int BT_ = B_ * T_;                         // 48
constexpr int R3_ = 3 * BT_;                         // 144
constexpr long long NN_ = (long long)N_ * N_;        // 4,000,000
constexpr int BTN_ = B_ * T_ * N_;                   // 96,000
constexpr float BETA_ = 0.01f, CW_ = 0.001f;
constexpr int RKS_ = 20;                             // r-GEMM split-K (fused x3)
constexpr int RKC_ = 100;                            // r-GEMM k-chunk
constexpr int KP3 = 3008;                            // K=3000 padded to 32
constexpr int KP2 = 2016;                            // K=2000 padded to 32

// ---------------------------------------------------------------------------
// Workspace layout (float offsets)
// ---------------------------------------------------------------------------
constexpr size_t OFF_OUT4 = 0;                                   // [B,T,N,D]
constexpr size_t OFF_LOWT = OFF_OUT4 + (size_t)BTN_ * D_;        // lowT^T [N][48]
constexpr size_t OFF_HVT  = OFF_LOWT + BTN_;                     // highV^T [N][48]
constexpr size_t OFF_ALIN = OFF_HVT + BTN_;                      // r^T [N][144]
constexpr size_t OFF_RT   = OFF_ALIN + (size_t)N_ * R3_;         // (unused, kept)
constexpr size_t OFF_P    = OFF_RT + (size_t)EA_ * R3_;          // P [144][9000]
constexpr size_t OFF_AOT  = OFF_P + (size_t)R3_ * 3 * EA_;       // (unused, kept)
constexpr size_t OFF_OT   = OFF_AOT + (size_t)EA_ * R3_;         // (unused, kept)
constexpr size_t OFF_O2P  = OFF_OT + (size_t)EA_ * R3_;          // out2 pre-p2 [B][T*N]
constexpr size_t OFF_OUTP = OFF_O2P + BTN_;                      // outp [B,T,N]
constexpr size_t OFF_O2F  = OFF_OUTP + BTN_;                     // out2 final [B,T,N]
constexpr size_t OFF_LI   = OFF_O2F + BTN_;                      // (spare)
constexpr size_t OFF_S    = OFF_LI + 8000;                       // G row sums [2000]
constexpr size_t OFF_RSL  = OFF_S + 2000;
constexpr size_t OFF_RSH  = OFF_RSL + 48;
constexpr size_t OFF_STP  = OFF_RSH + 48;
constexpr size_t OFF_STAT = OFF_STP + 3072;
constexpr size_t OFF_MMP  = OFF_STAT + 8;
constexpr size_t OFF_AB   = OFF_MMP + 384;
constexpr size_t OFF_CSP  = OFF_AB + 8;
constexpr size_t OFF_CS   = OFF_CSP + 48000;
constexpr size_t OFF_FEAT = OFF_CS + 3000;
constexpr size_t OFF_GATE = OFF_FEAT + 64;
constexpr size_t OFF_BAL  = OFF_GATE + 16;
constexpr size_t OFF_PART = ((OFF_BAL + 1 + 255) & ~(size_t)255); // split-K partials
constexpr size_t PARTCAP  = 13000000;                             // cap (floats)
// bf16 A-operand regions, k-octet-major [Kp/8][144][8] (sizes in floats)
constexpr size_t OFF_AT_LIN= OFF_PART + PARTCAP;                  // [KP2/8][144][8]
constexpr size_t OFF_AT_Q  = OFF_AT_LIN + (size_t)R3_ * KP2 / 2;
constexpr size_t OFF_AT_AO = OFF_AT_Q + (size_t)R3_ * KP3 / 2;
constexpr size_t OFF_AT_LL = OFF_AT_AO + (size_t)R3_ * KP3 / 2;
constexpr size_t OFF_G1B   = OFF_AT_LL + (size_t)R3_ * KP3 / 2;   // f1 bf16 [8000][32]
constexpr size_t OFF_G2B   = OFF_G1B + 128000;                    // f2 bf16 [8000][32]
// pre-transposed bf16 weights, k-octet-major [Kp/8][Nc][8]
constexpr size_t OFF_WTL   = OFF_G2B + 128000;                    // ltw^T  [KP2/8][3000][8]
constexpr size_t OFF_WTQ   = OFF_WTL + (size_t)EA_ * KP2 / 2;     // qkvw^T [KP3/8][9000][8]
constexpr size_t OFF_WTA   = OFF_WTQ + (size_t)3 * EA_ * KP3 / 2; // aow^T  [KP3/8][3000][8]
constexpr size_t OFF_WTLL  = OFF_WTA + (size_t)EA_ * KP3 / 2;     // llw^T  [KP3/8][2000][8]
} // namespace

typedef __attribute__((ext_vector_type(8))) short short8;
typedef __attribute__((ext_vector_type(4))) float f32x4;

// ---------------------------------------------------------------------------
// Helpers
// ---------------------------------------------------------------------------
__device__ __forceinline__ float waveReduceSum(float v) {
  for (int off = 32; off; off >>= 1) v += __shfl_down(v, off);
  return v;
}

__device__ __forceinline__ unsigned short f2bf(float x) {  // RNE fp32->bf16
  unsigned int u = __float_as_uint(x);
  unsigned int r = (u + 0x7FFFu + ((u >> 16) & 1u)) >> 16;
  return (unsigned short)r;
}

// k-octet-major A index: (row, k) -> [(k/8)][row][k%8]
__device__ __forceinline__ size_t aidx(int row, int k) {
  return ((size_t)(k >> 3) * R3_ + row) * 8 + (k & 7);
}

__device__ __forceinline__ void fma16(float* __restrict__ acc,
                                      const float4* __restrict__ a4, float bv) {
#pragma unroll
  for (int r4 = 0; r4 < 4; ++r4) {
    float4 av = a4[r4];
    acc[r4 * 4 + 0] = fmaf(av.x, bv, acc[r4 * 4 + 0]);
    acc[r4 * 4 + 1] = fmaf(av.y, bv, acc[r4 * 4 + 1]);
    acc[r4 * 4 + 2] = fmaf(av.z, bv, acc[r4 * 4 + 2]);
    acc[r4 * 4 + 3] = fmaf(av.w, bv, acc[r4 * 4 + 3]);
  }
}

// ---------------------------------------------------------------------------
__global__ void k_init(float* ws) {
  if (threadIdx.x == 0) ws[OFF_BAL] = 0.f;
}

__global__ void k_start(const float* __restrict__ x, const float* __restrict__ sw,
                        const float* __restrict__ sb, float* __restrict__ out4) {
  int i = blockIdx.x * 256 + threadIdx.x;
  if (i >= BTN_ * D_) return;
  int d = i & 15;
  out4[i] = fmaf(x[i >> 4], sw[d], sb[d]);
}

__global__ void k_feat(const float* __restrict__ out4, float* __restrict__ feat) {
  int b = blockIdx.x >> 4, d = blockIdx.x & 15;
  float s = 0.f;
  for (int tn = threadIdx.x; tn < T_ * N_; tn += 256)
    s += out4[((size_t)b * T_ * N_ + tn) * D_ + d];
  __shared__ float red[4];
  s = waveReduceSum(s);
  if ((threadIdx.x & 63) == 0) red[threadIdx.x >> 6] = s;
  __syncthreads();
  if (threadIdx.x == 0)
    feat[blockIdx.x] = (red[0] + red[1] + red[2] + red[3]) * (1.f / (T_ * N_));
}

__global__ void k_gate(const float* __restrict__ feat, const float* __restrict__ gw,
                       float* __restrict__ ws, int l) {
  __shared__ float lg[B_ * E_];
  int tid = threadIdx.x;
  if (tid < B_ * E_) {
    int b = tid >> 2, e = tid & 3;
    float s = 0.f;
    for (int d = 0; d < D_; ++d) s = fmaf(feat[b * D_ + d], gw[(l * D_ + d) * E_ + e], s);
    lg[tid] = s;
  }
  __syncthreads();
  if (tid == 0) {
    float* gates = ws + OFF_GATE;
    float imp[E_] = {0, 0, 0, 0}, load[E_] = {0, 0, 0, 0};
    for (int i = 0; i < B_ * E_; ++i) gates[i] = 0.f;
    for (int b = 0; b < B_; ++b) {
      const float* lb = lg + b * E_;
      int i1 = 0; float v1 = lb[0];
      for (int e = 1; e < E_; ++e) if (lb[e] > v1) { v1 = lb[e]; i1 = e; }
      int i2 = -1; float v2 = -1e30f;
      for (int e = 0; e < E_; ++e) { if (e == i1) continue; if (lb[e] > v2) { v2 = lb[e]; i2 = e; } }
      float e2 = expf(v2 - v1);
      float den = 1.f + e2;
      float g1 = 1.f / den, g2 = e2 / den;
      gates[b * E_ + i1] = g1; gates[b * E_ + i2] = g2;
      imp[i1] += g1; imp[i2] += g2; load[i1] += 1.f; load[i2] += 1.f;
    }
    float bal = 0.f;
    float m = 0.f; for (int e = 0; e < E_; ++e) m += imp[e]; m *= 0.25f;
    float v = 0.f; for (int e = 0; e < E_; ++e) { float d = imp[e] - m; v += d * d; } v *= 0.25f;
    bal += v / (m * m + 1e-10f);
    m = 0.f; for (int e = 0; e < E_; ++e) m += load[e]; m *= 0.25f;
    v = 0.f; for (int e = 0; e < E_; ++e) { float d = load[e] - m; v += d * d; } v *= 0.25f;
    bal += v / (m * m + 1e-10f);
    ws[OFF_BAL] += bal;
  }
}

// MoE expert apply; gelu via sigmoid identity
__global__ void k_expert(float* __restrict__ out4, const float* __restrict__ w1,
                         const float* __restrict__ b1, const float* __restrict__ w2,
                         const float* __restrict__ b2, const float* __restrict__ ws, int l) {
  int b = blockIdx.y;
  int tn = blockIdx.x * 256 + threadIdx.x;
  if (tn >= T_ * N_) return;
  float* row = out4 + ((size_t)b * T_ * N_ + tn) * D_;
  float r[D_], acc[D_];
#pragma unroll
  for (int d = 0; d < D_; ++d) { r[d] = row[d]; acc[d] = r[d]; }
  const float* gates = ws + OFF_GATE;
  for (int e = 0; e < E_; ++e) {
    float g = gates[b * E_ + e];
    if (g <= 0.f) continue;
    const float* W1 = w1 + (size_t)(l * E_ + e) * D_ * FF_;
    const float* B1 = b1 + (size_t)(l * E_ + e) * FF_;
    const float* W2 = w2 + (size_t)(l * E_ + e) * FF_ * D_;
    const float* B2 = b2 + (size_t)(l * E_ + e) * D_;
#pragma unroll 4
    for (int f = 0; f < FF_; ++f) {
      float p = B1[f];
#pragma unroll
      for (int d = 0; d < D_; ++d) p = fmaf(r[d], W1[d * FF_ + f], p);
      float c2 = 1.5957691216057308f * (p + 0.044715f * p * p * p);
      float e1 = __expf(-c2);
      float hv = p * __builtin_amdgcn_rcpf(1.f + e1);
      float gh = g * hv;
#pragma unroll
      for (int d = 0; d < D_; ++d) acc[d] = fmaf(gh, W2[f * D_ + d], acc[d]);
    }
#pragma unroll
    for (int d = 0; d < D_; ++d) acc[d] = fmaf(g, B2[d], acc[d]);
  }
#pragma unroll
  for (int d = 0; d < D_; ++d) row[d] = acc[d];
}

__global__ void k_wavelet(const float* __restrict__ x, const float* __restrict__ velo,
                          float* __restrict__ lowT, float* __restrict__ hvT) {
  int i = blockIdx.x * 256 + threadIdx.x;
  if (i >= BTN_) return;
  int b = i / (T_ * N_);
  int t = (i / N_) % T_;
  int n = i % N_;
  int ip = b * T_ * N_ + ((t + T_ - 1) % T_) * N_ + n;
  int row = t * B_ + b;
  lowT[(size_t)n * BT_ + row] = 0.5f * (x[i] + x[ip]);
  hvT[(size_t)n * BT_ + row] = 0.5f * (velo[i] - velo[ip]);
}

__global__ void k_rowsum(const float* __restrict__ lowT, const float* __restrict__ hvT,
                         float* __restrict__ ws) {
  int which = blockIdx.x / BT_;
  int row = blockIdx.x % BT_;
  const float* M = which ? hvT : lowT;
  float s = 0.f;
  for (int n = threadIdx.x; n < N_; n += 256) s += M[(size_t)n * BT_ + row];
  __shared__ float red[4];
  s = waveReduceSum(s);
  if ((threadIdx.x & 63) == 0) red[threadIdx.x >> 6] = s;
  __syncthreads();
  if (threadIdx.x == 0) ws[(which ? OFF_RSH : OFF_RSL) + row] = red[0] + red[1] + red[2] + red[3];
}

__global__ void k_S(const float* __restrict__ adj, const float* __restrict__ v0,
                    float* __restrict__ S) {
  int m = blockIdx.x;
  float vm = v0[m];
  const float* a = adj + (size_t)m * N_;
  float s = 0.f;
  for (int n = threadIdx.x; n < N_; n += 256) s += vm / a[n];
  __shared__ float red[4];
  s = waveReduceSum(s);
  if ((threadIdx.x & 63) == 0) red[threadIdx.x >> 6] = s;
  __syncthreads();
  if (threadIdx.x == 0) S[m] = red[0] + red[1] + red[2] + red[3];
}

// combine fused-stats partials (160 per matrix) -> {mu, 1/std}
__global__ void k_stats2(const float* __restrict__ stp, float* __restrict__ stat) {
  int z = blockIdx.x;
  const float* part = stp + (size_t)z * 1024;
  float s = 0.f, ss = 0.f;
  for (int i = threadIdx.x; i < 160; i += 256) { s += part[i * 2]; ss += part[i * 2 + 1]; }
  __shared__ float r1[4], r2[4];
  for (int off = 32; off; off >>= 1) { s += __shfl_down(s, off); ss += __shfl_down(ss, off); }
  if ((threadIdx.x & 63) == 0) { r1[threadIdx.x >> 6] = s; r2[threadIdx.x >> 6] = ss; }
  __syncthreads();
  if (threadIdx.x == 0) {
    float su = r1[0] + r1[1] + r1[2] + r1[3];
    float sq = r2[0] + r2[1] + r2[2] + r2[3];
    float mu = su * (1.f / (float)NN_);
    float var = sq * (1.f / (float)NN_) - mu * mu;
    stat[2 * z] = mu;
    stat[2 * z + 1] = 1.f / sqrtf(var);
  }
}

// ---------------------------------------------------------------------------
// Weight transpose+convert: W[K][Nc] fp32 -> Wt[(k/8)][Nc][8] bf16 (Kp padded).
// Coalesced read rows, LDS tile, coalesced 16B writes.
// ---------------------------------------------------------------------------
__global__ void k_wt(const float* __restrict__ W, unsigned short* __restrict__ Wt,
                     int K, int Nc) {
  __shared__ float t[32][65];
  int c0 = blockIdx.x * 64;
  int k0 = blockIdx.y * 32;
  int c = threadIdx.x & 63, kk = threadIdx.x >> 6;   // kk 0..3
#pragma unroll
  for (int j = 0; j < 8; ++j) {
    int k = kk * 8 + j;
    int gk = k0 + k, gc = c0 + c;
    float v = 0.f;
    if (gk < K && gc < Nc) v = W[(size_t)gk * Nc + gc];
    t[k][c] = v;
  }
  __syncthreads();
  int col = c0 + c;
  if (col >= Nc) return;
  short8 v;
#pragma unroll
  for (int j = 0; j < 8; ++j) v[j] = (short)f2bf(t[kk * 8 + j][c]);
  *(short8*)(Wt + ((size_t)(k0 / 8 + kk) * Nc + col) * 8) = v;
}

// ---------------------------------------------------------------------------
// Fused r-GEMMs, 16-row accumulators: blockIdx.z = z*3 + rg. Grid (8, RKS_, 9).
// rg==0 blocks also accumulate sum/sumsq of B (each element seen exactly once
// across the rg==0 sub-grid) -> stp[z][by*8+bx].
// ---------------------------------------------------------------------------
__global__ __launch_bounds__(256) void k_rgemm3(
    const float* __restrict__ lowT, const float* __restrict__ hvT,
    const float* __restrict__ lapd, const float* __restrict__ laph,
    const float* __restrict__ adj, const float* __restrict__ v0,
    const float* __restrict__ S, float* __restrict__ part,
    float* __restrict__ stp) {
  int zz = blockIdx.z;
  int z = zz / 3, rg = zz % 3;
  int col = blockIdx.x * 256 + threadIdx.x;
  int m0 = blockIdx.y * RKC_;
  int m1 = min(N_, m0 + RKC_);
  bool doStats = (rg == 0);
  float sAcc = 0.f, ssAcc = 0.f;
  float acc[16];
#pragma unroll
  for (int r = 0; r < 16; ++r) acc[r] = 0.f;
  if (col < N_) {
    const float* Abase = (z == 1 ? hvT : lowT);
    const float* ap = Abase + (size_t)m0 * BT_ + rg * 16;
    if (z != 1) {
      const float* Bm = z ? laph : lapd;
      const float* bp = Bm + (size_t)m0 * N_ + col;
      int len = m1 - m0;
      int ng = len >> 3;
      float bc[8];
      if (ng > 0) {
#pragma unroll
        for (int u = 0; u < 8; ++u) bc[u] = bp[(size_t)u * N_];
      }
      for (int gi = 0; gi < ng; ++gi) {
        float bn[8];
        bool more = (gi + 1 < ng);
        if (more) {
#pragma unroll
          for (int u = 0; u < 8; ++u) bn[u] = bp[(size_t)(8 + u) * N_];
        }
#pragma unroll
        for (int u = 0; u < 8; ++u) {
          fma16(acc, (const float4*)(ap + (size_t)u * BT_), bc[u]);
          if (doStats) { sAcc += bc[u]; ssAcc = fmaf(bc[u], bc[u], ssAcc); }
        }
        ap += (size_t)8 * BT_;
        bp += (size_t)8 * N_;
        if (more) {
#pragma unroll
          for (int u = 0; u < 8; ++u) bc[u] = bn[u];
        }
      }
      for (int m = m0 + (ng << 3); m < m1; ++m) {
        float bv = *bp;
        fma16(acc, (const float4*)ap, bv);
        if (doStats) { sAcc += bv; ssAcc = fmaf(bv, bv, ssAcc); }
        ap += BT_;
        bp += N_;
      }
    } else {
      const float* jp = adj + (size_t)m0 * N_ + col;
      int len = m1 - m0;
      int ng = len >> 3;
      float jc[8];
      if (ng > 0) {
#pragma unroll
        for (int u = 0; u < 8; ++u) jc[u] = jp[(size_t)u * N_];
      }
      int m = m0;
      for (int gi = 0; gi < ng; ++gi) {
        float jn[8];
        bool more = (gi + 1 < ng);
        if (more) {
#pragma unroll
          for (int u = 0; u < 8; ++u) jn[u] = jp[(size_t)(8 + u) * N_];
        }
#pragma unroll
        for (int u = 0; u < 8; ++u) {
          float bv = -(v0[m + u] / jc[u]);
          if (m + u == col) bv += S[m + u];
          fma16(acc, (const float4*)(ap + (size_t)u * BT_), bv);
          if (doStats) { sAcc += bv; ssAcc = fmaf(bv, bv, ssAcc); }
        }
        m += 8;
        ap += (size_t)8 * BT_;
        jp += (size_t)8 * N_;
        if (more) {
#pragma unroll
          for (int u = 0; u < 8; ++u) jc[u] = jn[u];
        }
      }
      for (; m < m1; ++m) {
        float bv = -(v0[m] / (*jp));
        if (m == col) bv += S[m];
        fma16(acc, (const float4*)ap, bv);
        if (doStats) { sAcc += bv; ssAcc = fmaf(bv, bv, ssAcc); }
        ap += BT_;
        jp += N_;
      }
    }
    float* pp = part + (((size_t)z * RKS_ + blockIdx.y) * BT_ + rg * 16) * N_ + col;
#pragma unroll
    for (int r = 0; r < 16; ++r) pp[(size_t)r * N_] = acc[r];
  }
  if (doStats) {
    __shared__ float r1[4], r2[4];
    float s = sAcc, ss = ssAcc;
    for (int off = 32; off; off >>= 1) { s += __shfl_down(s, off); ss += __shfl_down(ss, off); }
    if ((threadIdx.x & 63) == 0) { r1[threadIdx.x >> 6] = s; r2[threadIdx.x >> 6] = ss; }
    __syncthreads();
    if (threadIdx.x == 0) {
      float* p = stp + (size_t)z * 1024 + ((size_t)blockIdx.y * 8 + blockIdx.x) * 2;
      p[0] = r1[0] + r1[1] + r1[2] + r1[3];
      p[1] = r2[0] + r2[1] + r2[2] + r2[3];
    }
  }
}

// fused r epilogue -> ALIN + At_lin bf16 (k-octet-major)
__global__ void k_epiR3(const float* __restrict__ part, float* __restrict__ ws,
                        unsigned short* __restrict__ atl) {
  int z = blockIdx.z;
  int n = blockIdx.x * 256 + threadIdx.x;
  int row = blockIdx.y;
  if (n >= KP2) return;
  int arow = z * BT_ + row;
  if (n >= N_) { atl[aidx(arow, n)] = 0; return; }
  const float* base = part + (size_t)z * RKS_ * BT_ * N_;
  float s = 0.f;
  for (int ks = 0; ks < RKS_; ++ks) s += base[((size_t)(ks * BT_ + row)) * N_ + n];
  int statIdx = (z == 0) ? 0 : (z == 1 ? 4 : 2);
  size_t rsOff = (z == 1) ? OFF_RSH : OFF_RSL;
  float mu = ws[OFF_STAT + statIdx], isd = ws[OFF_STAT + statIdx + 1];
  float val = (s - mu * ws[rsOff + row]) * isd;
  ws[OFF_ALIN + (size_t)n * R3_ + arow] = val;
  atl[aidx(arow, n)] = f2bf(val);
}

// ---------------------------------------------------------------------------
// LDS-free MFMA GEMM: A and Bt both bf16 k-octet-major in global.
// Per wave: 2 col-fragments x 9 row-fragments = 18 MFMA/step; no barriers.
// part[ks][144][Nc].
// ---------------------------------------------------------------------------
__global__ __launch_bounds__(256) void k_mfmaB(
    const unsigned short* __restrict__ At, const unsigned short* __restrict__ Bt,
    float* __restrict__ part, int Nc, int Kp, int stepChunk) {
  int tid = threadIdx.x;
  int lane = tid & 63, w = tid >> 6;
  int lr = lane & 15, lo = lane >> 4;
  int colBase = blockIdx.x * 128;
  int col0 = colBase + w * 32 + lr;
  int col1 = col0 + 16;
  int c0 = min(col0, Nc - 1);     // clamp; OOB lanes' results never stored
  int c1 = min(col1, Nc - 1);
  int stepsTot = Kp / 32;
  int s0 = blockIdx.y * stepChunk;
  int s1 = min(stepsTot, s0 + stepChunk);

  f32x4 acc[18];
#pragma unroll
  for (int mt = 0; mt < 18; ++mt) {
    acc[mt][0] = 0.f; acc[mt][1] = 0.f; acc[mt][2] = 0.f; acc[mt][3] = 0.f;
  }

  const unsigned short* ap = At + ((size_t)(s0 * 4 + lo) * R3_ + lr) * 8;
  const unsigned short* bp0 = Bt + ((size_t)(s0 * 4 + lo) * Nc + c0) * 8;
  const unsigned short* bp1 = Bt + ((size_t)(s0 * 4 + lo) * Nc + c1) * 8;
  const size_t apStep = (size_t)4 * R3_ * 8;
  const size_t bStep = (size_t)4 * Nc * 8;
  for (int s = s0; s < s1; ++s) {
    short8 b0 = *(const short8*)bp0;
    short8 b1 = *(const short8*)bp1;
#pragma unroll
    for (int mt = 0; mt < 9; ++mt) {
      short8 a = *(const short8*)(ap + (size_t)mt * 128);
      acc[mt] = __builtin_amdgcn_mfma_f32_16x16x32_bf16(a, b0, acc[mt], 0, 0, 0);
      acc[9 + mt] = __builtin_amdgcn_mfma_f32_16x16x32_bf16(a, b1, acc[9 + mt], 0, 0, 0);
    }
    ap += apStep;
    bp0 += bStep;
    bp1 += bStep;
  }

#pragma unroll
  for (int half = 0; half < 2; ++half) {
    int gcol = colBase + w * 32 + half * 16 + lr;
    if (gcol < Nc) {
#pragma unroll
      for (int mt = 0; mt < 9; ++mt) {
        int row = mt * 16 + lo * 4;
        float* pp = part + ((size_t)blockIdx.y * R3_ + row) * Nc + gcol;
        f32x4 a = acc[half * 9 + mt];
        pp[0] = a[0];
        pp[(size_t)Nc] = a[1];
        pp[2 * (size_t)Nc] = a[2];
        pp[3 * (size_t)Nc] = a[3];
      }
    }
  }
}

// ---------------------------------------------------------------------------
// Epilogues
// ---------------------------------------------------------------------------
__global__ void k_minmax(const float* __restrict__ alin, float* __restrict__ mmp) {
  int g = blockIdx.y;
  float mn = 3.4e38f, mx = -3.4e38f;
  for (int i = blockIdx.x * 256 + threadIdx.x; i < N_ * BT_; i += 64 * 256) {
    int n = i / BT_, r = i % BT_;
    float v = alin[(size_t)n * R3_ + g * BT_ + r];
    mn = fminf(mn, v); mx = fmaxf(mx, v);
  }
  __shared__ float rn[4], rx[4];
  for (int off = 32; off; off >>= 1) {
    mn = fminf(mn, __shfl_down(mn, off));
    mx = fmaxf(mx, __shfl_down(mx, off));
  }
  if ((threadIdx.x & 63) == 0) { rn[threadIdx.x >> 6] = mn; rx[threadIdx.x >> 6] = mx; }
  __syncthreads();
  if (threadIdx.x == 0) {
    mn = fminf(fminf(rn[0], rn[1]), fminf(rn[2], rn[3]));
    mx = fmaxf(fmaxf(rx[0], rx[1]), fmaxf(rx[2], rx[3]));
    mmp[(size_t)(g * 64 + blockIdx.x) * 2] = mn;
    mmp[(size_t)(g * 64 + blockIdx.x) * 2 + 1] = mx;
  }
}

__global__ void k_minmax2(float* __restrict__ ws) {
  int g = blockIdx.x;
  int i = threadIdx.x;
  float mn = ws[OFF_MMP + (size_t)(g * 64 + i) * 2];
  float mx = ws[OFF_MMP + (size_t)(g * 64 + i) * 2 + 1];
  for (int off = 32; off; off >>= 1) {
    mn = fminf(mn, __shfl_down(mn, off));
    mx = fmaxf(mx, __shfl_down(mx, off));
  }
  if (i == 0) {
    float denom = fmaxf(mx - mn, 1e-8f);
    float a = 1.f / denom;
    ws[OFF_AB + g * 2] = a;
    ws[OFF_AB + g * 2 + 1] = -mn * a;
  }
}

__global__ void k_colsum(const float* __restrict__ ltw, float* __restrict__ csp) {
  int e = blockIdx.x * 256 + threadIdx.x;
  int ks = blockIdx.y;
  if (e >= EA_) return;
  float s = 0.f;
  for (int n = ks * 125; n < (ks + 1) * 125; ++n) s += ltw[(size_t)n * EA_ + e];
  csp[(size_t)ks * EA_ + e] = s;
}
__global__ void k_colsum2(float* __restrict__ ws) {
  int e = blockIdx.x * 256 + threadIdx.x;
  if (e >= EA_) return;
  float s = 0.f;
  for (int ks = 0; ks < 16; ++ks) s += ws[OFF_CSP + (size_t)ks * EA_ + e];
  ws[OFF_CS + e] = s;
}

__global__ void k_epiLin(const float* __restrict__ part, const float* __restrict__ ltb,
                         float* __restrict__ ws, unsigned short* __restrict__ atq,
                         int ksplit) {
  int e = blockIdx.x * 256 + threadIdx.x;
  int row = blockIdx.y;
  if (e >= KP3) return;
  if (e >= EA_) { atq[aidx(row, e)] = 0; return; }
  float s = 0.f;
  for (int ks = 0; ks < ksplit; ++ks) s += part[((size_t)(ks * R3_ + row)) * EA_ + e];
  int g = row / BT_;
  float a = ws[OFF_AB + g * 2], bb = ws[OFF_AB + g * 2 + 1];
  float val = fmaf(a, s, fmaf(bb, ws[OFF_CS + e], ltb[e]));
  atq[aidx(row, e)] = f2bf(val);
}

__global__ void k_epiQkv(const float* __restrict__ part, const float* __restrict__ qkvb,
                         float* __restrict__ P, int ksplit) {
  int c = blockIdx.x * 256 + threadIdx.x;
  int row = blockIdx.y;
  if (c >= 3 * EA_) return;
  float s = 0.f;
  for (int ks = 0; ks < ksplit; ++ks) s += part[((size_t)(ks * R3_ + row)) * (3 * EA_) + c];
  P[(size_t)row * (3 * EA_) + c] = s + qkvb[c];
}

// attention: waves cover t in parallel (wave-local reductions, one barrier)
__global__ void k_attn(const float* __restrict__ P, unsigned short* __restrict__ atao) {
  int mha = blockIdx.y;
  int s_ = blockIdx.x / (B_ * H_);
  int rem = blockIdx.x % (B_ * H_);
  int b = rem / H_, h = rem % H_;
  const int pq[3] = {0, 1, 2}, pk[3] = {1, 2, 0}, pv[3] = {2, 0, 1};
  const float* qrow = P + ((size_t)(pq[mha] * BT_ + s_ * B_ + b)) * (3 * EA_) + h * HD_;
  __shared__ float sc[T_];
  int w = threadIdx.x >> 6, lane = threadIdx.x & 63;
  for (int t = w; t < T_; t += 4) {
    const float* krow = P + ((size_t)(pk[mha] * BT_ + t * B_ + b)) * (3 * EA_) + EA_ + h * HD_;
    float p = 0.f;
    for (int d = lane; d < HD_; d += 64) p = fmaf(qrow[d], krow[d], p);
    p = waveReduceSum(p);
    if (lane == 0) sc[t] = p * 0.031622776601683794f;
  }
  __syncthreads();
  float a[T_];
  float m = sc[0];
#pragma unroll
  for (int t = 1; t < T_; ++t) m = fmaxf(m, sc[t]);
  float sum = 0.f;
#pragma unroll
  for (int t = 0; t < T_; ++t) { a[t] = expf(sc[t] - m); sum += a[t]; }
  float inv = 1.f / sum;
#pragma unroll
  for (int t = 0; t < T_; ++t) a[t] *= inv;
  int orow = mha * BT_ + s_ * B_ + b;
  for (int d = threadIdx.x; d < HD_; d += 256) {
    float o = 0.f;
#pragma unroll
    for (int t = 0; t < T_; ++t)
      o = fmaf(a[t], P[((size_t)(pv[mha] * BT_ + t * B_ + b)) * (3 * EA_) + 2 * EA_ + h * HD_ + d], o);
    atao[aidx(orow, h * HD_ + d)] = f2bf(o);
  }
  if (h == 0 && threadIdx.x < 8) atao[aidx(orow, EA_ + threadIdx.x)] = 0;
}

__global__ void k_epiAO(const float* __restrict__ part, const float* __restrict__ aob,
                        unsigned short* __restrict__ atll, int ksplit) {
  int c = blockIdx.x * 256 + threadIdx.x;
  int row = blockIdx.y;
  if (c >= KP3) return;
  if (c >= EA_) { atll[aidx(row, c)] = 0; return; }
  float s = 0.f;
  for (int ks = 0; ks < ksplit; ++ks) s += part[((size_t)(ks * R3_ + row)) * EA_ + c];
  atll[aidx(row, c)] = f2bf(s + aob[c]);
}

__global__ void k_epiLL(const float* __restrict__ part, const float* __restrict__ llb,
                        float* __restrict__ o2p, int ksplit) {
  int n = blockIdx.x * 256 + threadIdx.x;
  int row = blockIdx.y;  // t*B+b
  if (n >= N_) return;
  float s = 0.f;
  for (int g = 0; g < 3; ++g)
    for (int ks = 0; ks < ksplit; ++ks)
      s += part[((size_t)(ks * R3_ + g * BT_ + row)) * N_ + n];
  int t = row / B_, b = row % B_;
  o2p[(size_t)b * (T_ * N_) + t * N_ + n] = BETA_ * (s + 3.f * llb[n]);
}

__global__ void k_proj(const float* __restrict__ out4, const float* __restrict__ pw,
                       const float* __restrict__ pb, float* __restrict__ outp) {
  int i = blockIdx.x * 256 + threadIdx.x;
  if (i >= BTN_) return;
  int b = i / (T_ * N_);
  int t = (i / N_) % T_;
  int n = i % N_;
  float acc = pb[t];
  for (int t2 = 0; t2 < T_; ++t2) {
    const float* o = out4 + ((size_t)(b * T_ + t2) * N_ + n) * D_;
#pragma unroll
    for (int d = 0; d < D_; ++d) acc = fmaf(o[d], pw[(t2 * D_ + d) * T_ + t], acc);
  }
  outp[i] = acc;
}

__global__ void k_p2(const float* __restrict__ o2p, const float* __restrict__ p2w,
                     const float* __restrict__ p2b, float* __restrict__ o2f) {
  int i = blockIdx.x * 256 + threadIdx.x;
  if (i >= BTN_) return;
  int b = i / (T_ * N_);
  int t = (i / N_) % T_;
  int n = i % N_;
  float acc = p2b[t];
  const float* src = o2p + (size_t)b * (T_ * N_) + (size_t)n * T_;
#pragma unroll
  for (int c = 0; c < T_; ++c) acc = fmaf(src[c], p2w[c * T_ + t], acc);
  o2f[i] = acc;
}

// fused: out3 write + f-normalization -> bf16 padded rows g1b/g2b [8000][32]
__global__ void k_fng(const float* __restrict__ outp, const float* __restrict__ o2f,
                      float* __restrict__ dout, unsigned short* __restrict__ g1b,
                      unsigned short* __restrict__ g2b) {
  int r = blockIdx.x * 256 + threadIdx.x;
  if (r >= B_ * N_) return;
  int b = r / N_, n = r % N_;
  float v1[T_], v2[T_];
  float s1 = 0.f, s2 = 0.f;
#pragma unroll
  for (int t = 0; t < T_; ++t) {
    size_t idx = (size_t)b * T_ * N_ + (size_t)t * N_ + n;
    v1[t] = outp[idx];
    v2[t] = o2f[idx];
    dout[idx] = v1[t] + v2[t];
    s1 = fmaf(v1[t], v1[t], s1);
    s2 = fmaf(v2[t], v2[t], s2);
  }
  float n1 = fmaxf(sqrtf(s1), 1e-12f), n2 = fmaxf(sqrtf(s2), 1e-12f);
  float i1 = 10.f / n1, i2 = 1.f / n2;
  unsigned short q[32], z[32];
#pragma unroll
  for (int t = 0; t < T_; ++t) { q[t] = f2bf(v1[t] * i1); z[t] = f2bf(v2[t] * i2); }
#pragma unroll
  for (int t = T_; t < 32; ++t) { q[t] = 0; z[t] = 0; }
  short8* qd = (short8*)(g1b + (size_t)r * 32);
  short8* zd = (short8*)(g2b + (size_t)r * 32);
#pragma unroll
  for (int c = 0; c < 4; ++c) {
    short8 pv, pz;
#pragma unroll
    for (int e = 0; e < 8; ++e) { pv[e] = (short)q[c * 8 + e]; pz[e] = (short)z[c * 8 + e]; }
    qd[c] = pv;
    zd[c] = pz;
  }
}

// MFMA logsumexp: per block 16 q-rows; 16 j-slices (4 waves x grid.y=4)
__global__ __launch_bounds__(256) void k_lsemf(const unsigned short* __restrict__ g1b,
                                               const unsigned short* __restrict__ g2b,
                                               float* __restrict__ psm,
                                               float* __restrict__ psd) {
  int lane = threadIdx.x & 63, w = threadIdx.x >> 6;
  int lr = lane & 15, lo = lane >> 4;
  int i0 = blockIdx.x * 16;
  int slice = blockIdx.y * 4 + w;     // 0..15
  short8 a = *(const short8*)(g1b + (size_t)(i0 + lr) * 32 + lo * 8);
  float sm[4] = {0.f, 0.f, 0.f, 0.f};
  float sd[4] = {0.f, 0.f, 0.f, 0.f};
  for (int t = slice; t < 500; t += 16) {
    int j0 = t * 16;
    short8 b = *(const short8*)(g2b + (size_t)(j0 + lr) * 32 + lo * 8);
    f32x4 acc = {0.f, 0.f, 0.f, 0.f};
    acc = __builtin_amdgcn_mfma_f32_16x16x32_bf16(a, b, acc, 0, 0, 0);
#pragma unroll
    for (int rg = 0; rg < 4; ++rg) {
      float s = acc[rg];
      sm[rg] += __expf(s);
      if (j0 + lr == i0 + lo * 4 + rg) sd[rg] = s;
    }
  }
#pragma unroll
  for (int off = 1; off < 16; off <<= 1) {
#pragma unroll
    for (int rg = 0; rg < 4; ++rg) {
      sm[rg] += __shfl_xor(sm[rg], off);
      sd[rg] += __shfl_xor(sd[rg], off);
    }
  }
  __shared__ float lsm[4][16], lsd[4][16];
  if (lr == 0) {
#pragma unroll
    for (int rg = 0; rg < 4; ++rg) {
      lsm[w][lo * 4 + rg] = sm[rg];
      lsd[w][lo * 4 + rg] = sd[rg];
    }
  }
  __syncthreads();
  if (threadIdx.x < 16) {
    float m = lsm[0][threadIdx.x] + lsm[1][threadIdx.x] + lsm[2][threadIdx.x] + lsm[3][threadIdx.x];
    float d = lsd[0][threadIdx.x] + lsd[1][threadIdx.x] + lsd[2][threadIdx.x] + lsd[3][threadIdx.x];
    psm[(size_t)blockIdx.y * 8000 + i0 + threadIdx.x] = m;
    psd[(size_t)blockIdx.y * 8000 + i0 + threadIdx.x] = d;
  }
}

// fused: combine j-splits + mean + final scalars
__global__ __launch_bounds__(1024) void k_lsefin(const float* __restrict__ psm,
                                                 const float* __restrict__ psd,
                                                 const float* __restrict__ ws,
                                                 float* __restrict__ dout) {
  float acc = 0.f;
  for (int r = threadIdx.x; r < B_ * N_; r += 1024) {
    float sm = psm[r] + psm[8000 + r] + psm[16000 + r] + psm[24000 + r];
    float sd = psd[r] + psd[8000 + r] + psd[16000 + r] + psd[24000 + r];
    acc += sd - logf(sm);
  }
  __shared__ float red[16];
  acc = waveReduceSum(acc);
  if ((threadIdx.x & 63) == 0) red[threadIdx.x >> 6] = acc;
  __syncthreads();
  if (threadIdx.x == 0) {
    float s = 0.f;
    for (int i = 0; i < 16; ++i) s += red[i];
    float closs = -s * (1.f / (B_ * N_));
    dout[BTN_] = ws[OFF_BAL];
    dout[BTN_ + 1] = CW_ * closs;
  }
}

// ---------------------------------------------------------------------------
extern "C" void kernel_launch(void* const* d_in, const int* in_sizes, int n_in,
                              void* d_out, int out_size, void* d_ws, size_t ws_size,
                              hipStream_t stream) {
  const float* x    = (const float*)d_in[0];
  const float* velo = (const float*)d_in[1];
  const float* adj  = (const float*)d_in[2];
  const float* lapd = (const float*)d_in[3];
  const float* laph = (const float*)d_in[4];
  const float* sw   = (const float*)d_in[5];
  const float* sb   = (const float*)d_in[6];
  const float* gw   = (const float*)d_in[7];
  const float* ew1  = (const float*)d_in[8];
  const float* eb1  = (const float*)d_in[9];
  const float* ew2  = (const float*)d_in[10];
  const float* eb2  = (const float*)d_in[11];
  const float* pw   = (const float*)d_in[12];
  const float* pb   = (const float*)d_in[13];
  const float* ltw  = (const float*)d_in[14];
  const float* ltb  = (const float*)d_in[15];
  const float* qkvw = (const float*)d_in[16];
  const float* qkvb = (const float*)d_in[17];
  const float* aow  = (const float*)d_in[18];
  const float* aob  = (const float*)d_in[19];
  const float* llw  = (const float*)d_in[20];
  const float* llb  = (const float*)d_in[21];
  const float* p2w  = (const float*)d_in[22];
  const float* p2b  = (const float*)d_in[23];
  float* ws = (float*)d_ws;
  float* dout = (float*)d_out;
  const float* v0 = velo;  // velo[0,0,:]
  float* part = ws + OFF_PART;
  unsigned short* atLin = (unsigned short*)(ws + OFF_AT_LIN);
  unsigned short* atQ   = (unsigned short*)(ws + OFF_AT_Q);
  unsigned short* atAO  = (unsigned short*)(ws + OFF_AT_AO);
  unsigned short* atLL  = (unsigned short*)(ws + OFF_AT_LL);
  unsigned short* g1b   = (unsigned short*)(ws + OFF_G1B);
  unsigned short* g2b   = (unsigned short*)(ws + OFF_G2B);
  unsigned short* wtL   = (unsigned short*)(ws + OFF_WTL);
  unsigned short* wtQ   = (unsigned short*)(ws + OFF_WTQ);
  unsigned short* wtA   = (unsigned short*)(ws + OFF_WTA);
  unsigned short* wtLL  = (unsigned short*)(ws + OFF_WTLL);
  dim3 b256(256);

  k_init<<<dim3(1), dim3(64), 0, stream>>>(ws);

  // weight transposes (input-only deps; run up front)
  k_wt<<<dim3(47, 63), b256, 0, stream>>>(ltw, wtL, N_, EA_);          // [2000][3000] -> KP2
  k_wt<<<dim3(141, 94), b256, 0, stream>>>(qkvw, wtQ, EA_, 3 * EA_);   // [3000][9000] -> KP3
  k_wt<<<dim3(47, 94), b256, 0, stream>>>(aow, wtA, EA_, EA_);         // [3000][3000] -> KP3
  k_wt<<<dim3(32, 94), b256, 0, stream>>>(llw, wtLL, EA_, N_);         // [3000][2000] -> KP3

  k_start<<<dim3((BTN_ * D_ + 255) / 256), b256, 0, stream>>>(x, sw, sb, ws + OFF_OUT4);

  for (int l = 0; l < L_; ++l) {
    k_feat<<<dim3(B_ * D_), b256, 0, stream>>>(ws + OFF_OUT4, ws + OFF_FEAT);
    k_gate<<<dim3(1), dim3(64), 0, stream>>>(ws + OFF_FEAT, gw, ws, l);
    k_expert<<<dim3((T_ * N_ + 255) / 256, B_), b256, 0, stream>>>(ws + OFF_OUT4, ew1, eb1, ew2, eb2, ws, l);
  }

  k_wavelet<<<dim3((BTN_ + 255) / 256), b256, 0, stream>>>(x, velo, ws + OFF_LOWT, ws + OFF_HVT);
  k_rowsum<<<dim3(2 * BT_), b256, 0, stream>>>(ws + OFF_LOWT, ws + OFF_HVT, ws);
  k_S<<<dim3(N_), b256, 0, stream>>>(adj, v0, ws + OFF_S);

  // fused r1/r2/r3 GEMMs (with in-line B stats) then stats reduce + epilogue
  k_rgemm3<<<dim3(8, RKS_, 9), b256, 0, stream>>>(ws + OFF_LOWT, ws + OFF_HVT, lapd, laph,
                                                  adj, v0, ws + OFF_S, part, ws + OFF_STP);
  k_stats2<<<dim3(3), b256, 0, stream>>>(ws + OFF_STP, ws + OFF_STAT);
  k_epiR3<<<dim3(8, 48, 3), b256, 0, stream>>>(part, ws, atLin);

  k_minmax<<<dim3(64, 3), b256, 0, stream>>>(ws + OFF_ALIN, ws + OFF_MMP);
  k_minmax2<<<dim3(3), dim3(64), 0, stream>>>(ws);
  k_colsum<<<dim3(12, 16), b256, 0, stream>>>(ltw, ws + OFF_CSP);
  k_colsum2<<<dim3(12), b256, 0, stream>>>(ws);

  // lin (LDS-free MFMA): 16 splits x 4 steps (63 steps)
  k_mfmaB<<<dim3(24, 16), b256, 0, stream>>>(atLin, wtL, part, EA_, KP2, 4);
  k_epiLin<<<dim3(12, 144), b256, 0, stream>>>(part, ltb, ws, atQ, 16);

  // qkv (LDS-free MFMA): 10 splits x 10 steps (94 steps)
  k_mfmaB<<<dim3(71, 10), b256, 0, stream>>>(atQ, wtQ, part, 3 * EA_, KP3, 10);
  k_epiQkv<<<dim3(36, 144), b256, 0, stream>>>(part, qkvb, ws + OFF_P, 10);

  // attention
  k_attn<<<dim3(T_ * B_ * H_, 3), b256, 0, stream>>>(ws + OFF_P, atAO);

  // attn-out (LDS-free MFMA): 16 splits x 6 steps
  k_mfmaB<<<dim3(24, 16), b256, 0, stream>>>(atAO, wtA, part, EA_, KP3, 6);
  k_epiAO<<<dim3(12, 144), b256, 0, stream>>>(part, aob, atLL, 16);

  // ll (LDS-free MFMA): 20 splits x 5 steps
  k_mfmaB<<<dim3(16, 20), b256, 0, stream>>>(atLL, wtLL, part, N_, KP3, 5);
  k_epiLL<<<dim3(8, 48), b256, 0, stream>>>(part, llb, ws + OFF_O2P, 20);

  k_proj<<<dim3((BTN_ + 255) / 256), b256, 0, stream>>>(ws + OFF_OUT4, pw, pb, ws + OFF_OUTP);
  k_p2<<<dim3((BTN_ + 255) / 256), b256, 0, stream>>>(ws + OFF_O2P, p2w, p2b, ws + OFF_O2F);

  // fused out3 + fnorm (writes dout body + bf16 g1b/g2b)
  k_fng<<<dim3((B_ * N_ + 255) / 256), b256, 0, stream>>>(ws + OFF_OUTP, ws + OFF_O2F, dout, g1b, g2b);

  // MFMA logsumexp; psm/psd partials live in `part`
  k_lsemf<<<dim3(500, 4), b256, 0, stream>>>(g1b, g2b, part, part + 32000);
  k_lsefin<<<dim3(1), dim3(1024), 0, stream>>>(part, part + 32000, ws, dout);
}

// Round 21
// 502.244 us; speedup vs baseline: 1.1024x; 1.1024x over previous
//
#include <hip/hip_runtime.h>
#include <math.h>

// ---------------------------------------------------------------------------
// Model constants
// ---------------------------------------------------------------------------
namespace {
constexpr int B_ = 4, T_ = 12, N_ = 2000, D_ = 16, FF_ = 64, E_ = 4, L_ = 2;
constexpr int EA_ = 3000, H_ = 3, HD_ = EA_ / H_;   // 1000
constexpr int BT_ = B_ * T_;                         // 48
constexpr int R3_ = 3 * BT_;                         // 144
constexpr long long NN_ = (long long)N_ * N_;        // 4,000,000
constexpr int BTN_ = B_ * T_ * N_;                   // 96,000
constexpr float BETA_ = 0.01f, CW_ = 0.001f;
constexpr int RKS_ = 20;                             // r-GEMM split-K (fused x3)
constexpr int RKC_ = 100;                            // r-GEMM k-chunk
constexpr int KP3 = 3008;                            // K=3000 padded to 32
constexpr int KP2 = 2016;                            // K=2000 padded to 32

// ---------------------------------------------------------------------------
// Workspace layout (float offsets)
// ---------------------------------------------------------------------------
constexpr size_t OFF_OUT4 = 0;                                   // [B,T,N,D]
constexpr size_t OFF_LOWT = OFF_OUT4 + (size_t)BTN_ * D_;        // lowT^T [N][48]
constexpr size_t OFF_HVT  = OFF_LOWT + BTN_;                     // highV^T [N][48]
constexpr size_t OFF_ALIN = OFF_HVT + BTN_;                      // r^T [N][144]
constexpr size_t OFF_RT   = OFF_ALIN + (size_t)N_ * R3_;         // (unused, kept)
constexpr size_t OFF_P    = OFF_RT + (size_t)EA_ * R3_;          // P [144][9000]
constexpr size_t OFF_AOT  = OFF_P + (size_t)R3_ * 3 * EA_;       // (unused, kept)
constexpr size_t OFF_OT   = OFF_AOT + (size_t)EA_ * R3_;         // (unused, kept)
constexpr size_t OFF_O2P  = OFF_OT + (size_t)EA_ * R3_;          // out2 pre-p2 [B][T*N]
constexpr size_t OFF_OUTP = OFF_O2P + BTN_;                      // outp [B,T,N]
constexpr size_t OFF_O2F  = OFF_OUTP + BTN_;                     // out2 final [B,T,N]
constexpr size_t OFF_LI   = OFF_O2F + BTN_;                      // (spare)
constexpr size_t OFF_S    = OFF_LI + 8000;                       // G row sums [2000]
constexpr size_t OFF_RSL  = OFF_S + 2000;
constexpr size_t OFF_RSH  = OFF_RSL + 48;
constexpr size_t OFF_STP  = OFF_RSH + 48;
constexpr size_t OFF_STAT = OFF_STP + 3072;
constexpr size_t OFF_MMP  = OFF_STAT + 8;
constexpr size_t OFF_AB   = OFF_MMP + 384;
constexpr size_t OFF_CSP  = OFF_AB + 8;
constexpr size_t OFF_CS   = OFF_CSP + 48000;
constexpr size_t OFF_FEAT = OFF_CS + 3000;
constexpr size_t OFF_GATE = OFF_FEAT + 64;
constexpr size_t OFF_BAL  = OFF_GATE + 16;
constexpr size_t OFF_PART = ((OFF_BAL + 1 + 255) & ~(size_t)255); // split-K partials
constexpr size_t PARTCAP  = 13000000;                             // cap (floats)
// bf16 A-operand regions, k-octet-major [Kp/8][144][8] (sizes in floats)
constexpr size_t OFF_AT_LIN= OFF_PART + PARTCAP;                  // [KP2/8][144][8]
constexpr size_t OFF_AT_Q  = OFF_AT_LIN + (size_t)R3_ * KP2 / 2;
constexpr size_t OFF_AT_AO = OFF_AT_Q + (size_t)R3_ * KP3 / 2;
constexpr size_t OFF_AT_LL = OFF_AT_AO + (size_t)R3_ * KP3 / 2;
constexpr size_t OFF_G1B   = OFF_AT_LL + (size_t)R3_ * KP3 / 2;   // f1 bf16 [8000][32]
constexpr size_t OFF_G2B   = OFF_G1B + 128000;                    // f2 bf16 [8000][32]
} // namespace

typedef __attribute__((ext_vector_type(8))) short short8;
typedef __attribute__((ext_vector_type(4))) float f32x4;

// ---------------------------------------------------------------------------
// Helpers
// ---------------------------------------------------------------------------
__device__ __forceinline__ float waveReduceSum(float v) {
  for (int off = 32; off; off >>= 1) v += __shfl_down(v, off);
  return v;
}

__device__ __forceinline__ unsigned short f2bf(float x) {  // RNE fp32->bf16
  unsigned int u = __float_as_uint(x);
  unsigned int r = (u + 0x7FFFu + ((u >> 16) & 1u)) >> 16;
  return (unsigned short)r;
}

__device__ __forceinline__ unsigned int pk2(float hi, float lo) {
  return ((unsigned int)f2bf(hi) << 16) | f2bf(lo);
}

// k-octet-major A index: (row, k) -> [(k/8)][row][k%8]
__device__ __forceinline__ size_t aidx(int row, int k) {
  return ((size_t)(k >> 3) * R3_ + row) * 8 + (k & 7);
}

__device__ __forceinline__ void fma16(float* __restrict__ acc,
                                      const float4* __restrict__ a4, float bv) {
#pragma unroll
  for (int r4 = 0; r4 < 4; ++r4) {
    float4 av = a4[r4];
    acc[r4 * 4 + 0] = fmaf(av.x, bv, acc[r4 * 4 + 0]);
    acc[r4 * 4 + 1] = fmaf(av.y, bv, acc[r4 * 4 + 1]);
    acc[r4 * 4 + 2] = fmaf(av.z, bv, acc[r4 * 4 + 2]);
    acc[r4 * 4 + 3] = fmaf(av.w, bv, acc[r4 * 4 + 3]);
  }
}

// ---------------------------------------------------------------------------
__global__ void k_init(float* ws) {
  if (threadIdx.x == 0) ws[OFF_BAL] = 0.f;
}

__global__ void k_start(const float* __restrict__ x, const float* __restrict__ sw,
                        const float* __restrict__ sb, float* __restrict__ out4) {
  int i = blockIdx.x * 256 + threadIdx.x;
  if (i >= BTN_ * D_) return;
  int d = i & 15;
  out4[i] = fmaf(x[i >> 4], sw[d], sb[d]);
}

__global__ void k_feat(const float* __restrict__ out4, float* __restrict__ feat) {
  int b = blockIdx.x >> 4, d = blockIdx.x & 15;
  float s = 0.f;
  for (int tn = threadIdx.x; tn < T_ * N_; tn += 256)
    s += out4[((size_t)b * T_ * N_ + tn) * D_ + d];
  __shared__ float red[4];
  s = waveReduceSum(s);
  if ((threadIdx.x & 63) == 0) red[threadIdx.x >> 6] = s;
  __syncthreads();
  if (threadIdx.x == 0)
    feat[blockIdx.x] = (red[0] + red[1] + red[2] + red[3]) * (1.f / (T_ * N_));
}

__global__ void k_gate(const float* __restrict__ feat, const float* __restrict__ gw,
                       float* __restrict__ ws, int l) {
  __shared__ float lg[B_ * E_];
  int tid = threadIdx.x;
  if (tid < B_ * E_) {
    int b = tid >> 2, e = tid & 3;
    float s = 0.f;
    for (int d = 0; d < D_; ++d) s = fmaf(feat[b * D_ + d], gw[(l * D_ + d) * E_ + e], s);
    lg[tid] = s;
  }
  __syncthreads();
  if (tid == 0) {
    float* gates = ws + OFF_GATE;
    float imp[E_] = {0, 0, 0, 0}, load[E_] = {0, 0, 0, 0};
    for (int i = 0; i < B_ * E_; ++i) gates[i] = 0.f;
    for (int b = 0; b < B_; ++b) {
      const float* lb = lg + b * E_;
      int i1 = 0; float v1 = lb[0];
      for (int e = 1; e < E_; ++e) if (lb[e] > v1) { v1 = lb[e]; i1 = e; }
      int i2 = -1; float v2 = -1e30f;
      for (int e = 0; e < E_; ++e) { if (e == i1) continue; if (lb[e] > v2) { v2 = lb[e]; i2 = e; } }
      float e2 = expf(v2 - v1);
      float den = 1.f + e2;
      float g1 = 1.f / den, g2 = e2 / den;
      gates[b * E_ + i1] = g1; gates[b * E_ + i2] = g2;
      imp[i1] += g1; imp[i2] += g2; load[i1] += 1.f; load[i2] += 1.f;
    }
    float bal = 0.f;
    float m = 0.f; for (int e = 0; e < E_; ++e) m += imp[e]; m *= 0.25f;
    float v = 0.f; for (int e = 0; e < E_; ++e) { float d = imp[e] - m; v += d * d; } v *= 0.25f;
    bal += v / (m * m + 1e-10f);
    m = 0.f; for (int e = 0; e < E_; ++e) m += load[e]; m *= 0.25f;
    v = 0.f; for (int e = 0; e < E_; ++e) { float d = load[e] - m; v += d * d; } v *= 0.25f;
    bal += v / (m * m + 1e-10f);
    ws[OFF_BAL] += bal;
  }
}

// MoE expert apply; gelu via sigmoid identity
__global__ void k_expert(float* __restrict__ out4, const float* __restrict__ w1,
                         const float* __restrict__ b1, const float* __restrict__ w2,
                         const float* __restrict__ b2, const float* __restrict__ ws, int l) {
  int b = blockIdx.y;
  int tn = blockIdx.x * 256 + threadIdx.x;
  if (tn >= T_ * N_) return;
  float* row = out4 + ((size_t)b * T_ * N_ + tn) * D_;
  float r[D_], acc[D_];
#pragma unroll
  for (int d = 0; d < D_; ++d) { r[d] = row[d]; acc[d] = r[d]; }
  const float* gates = ws + OFF_GATE;
  for (int e = 0; e < E_; ++e) {
    float g = gates[b * E_ + e];
    if (g <= 0.f) continue;
    const float* W1 = w1 + (size_t)(l * E_ + e) * D_ * FF_;
    const float* B1 = b1 + (size_t)(l * E_ + e) * FF_;
    const float* W2 = w2 + (size_t)(l * E_ + e) * FF_ * D_;
    const float* B2 = b2 + (size_t)(l * E_ + e) * D_;
#pragma unroll 4
    for (int f = 0; f < FF_; ++f) {
      float p = B1[f];
#pragma unroll
      for (int d = 0; d < D_; ++d) p = fmaf(r[d], W1[d * FF_ + f], p);
      float c2 = 1.5957691216057308f * (p + 0.044715f * p * p * p);
      float e1 = __expf(-c2);
      float hv = p * __builtin_amdgcn_rcpf(1.f + e1);
      float gh = g * hv;
#pragma unroll
      for (int d = 0; d < D_; ++d) acc[d] = fmaf(gh, W2[f * D_ + d], acc[d]);
    }
#pragma unroll
    for (int d = 0; d < D_; ++d) acc[d] = fmaf(g, B2[d], acc[d]);
  }
#pragma unroll
  for (int d = 0; d < D_; ++d) row[d] = acc[d];
}

__global__ void k_wavelet(const float* __restrict__ x, const float* __restrict__ velo,
                          float* __restrict__ lowT, float* __restrict__ hvT) {
  int i = blockIdx.x * 256 + threadIdx.x;
  if (i >= BTN_) return;
  int b = i / (T_ * N_);
  int t = (i / N_) % T_;
  int n = i % N_;
  int ip = b * T_ * N_ + ((t + T_ - 1) % T_) * N_ + n;
  int row = t * B_ + b;
  lowT[(size_t)n * BT_ + row] = 0.5f * (x[i] + x[ip]);
  hvT[(size_t)n * BT_ + row] = 0.5f * (velo[i] - velo[ip]);
}

__global__ void k_rowsum(const float* __restrict__ lowT, const float* __restrict__ hvT,
                         float* __restrict__ ws) {
  int which = blockIdx.x / BT_;
  int row = blockIdx.x % BT_;
  const float* M = which ? hvT : lowT;
  float s = 0.f;
  for (int n = threadIdx.x; n < N_; n += 256) s += M[(size_t)n * BT_ + row];
  __shared__ float red[4];
  s = waveReduceSum(s);
  if ((threadIdx.x & 63) == 0) red[threadIdx.x >> 6] = s;
  __syncthreads();
  if (threadIdx.x == 0) ws[(which ? OFF_RSH : OFF_RSL) + row] = red[0] + red[1] + red[2] + red[3];
}

__global__ void k_S(const float* __restrict__ adj, const float* __restrict__ v0,
                    float* __restrict__ S) {
  int m = blockIdx.x;
  float vm = v0[m];
  const float* a = adj + (size_t)m * N_;
  float s = 0.f;
  for (int n = threadIdx.x; n < N_; n += 256) s += vm / a[n];
  __shared__ float red[4];
  s = waveReduceSum(s);
  if ((threadIdx.x & 63) == 0) red[threadIdx.x >> 6] = s;
  __syncthreads();
  if (threadIdx.x == 0) S[m] = red[0] + red[1] + red[2] + red[3];
}

// combine fused-stats partials (160 per matrix) -> {mu, 1/std}
__global__ void k_stats2(const float* __restrict__ stp, float* __restrict__ stat) {
  int z = blockIdx.x;
  const float* part = stp + (size_t)z * 1024;
  float s = 0.f, ss = 0.f;
  for (int i = threadIdx.x; i < 160; i += 256) { s += part[i * 2]; ss += part[i * 2 + 1]; }
  __shared__ float r1[4], r2[4];
  for (int off = 32; off; off >>= 1) { s += __shfl_down(s, off); ss += __shfl_down(ss, off); }
  if ((threadIdx.x & 63) == 0) { r1[threadIdx.x >> 6] = s; r2[threadIdx.x >> 6] = ss; }
  __syncthreads();
  if (threadIdx.x == 0) {
    float su = r1[0] + r1[1] + r1[2] + r1[3];
    float sq = r2[0] + r2[1] + r2[2] + r2[3];
    float mu = su * (1.f / (float)NN_);
    float var = sq * (1.f / (float)NN_) - mu * mu;
    stat[2 * z] = mu;
    stat[2 * z + 1] = 1.f / sqrtf(var);
  }
}

// ---------------------------------------------------------------------------
// Fused r-GEMMs, 16-row accumulators: blockIdx.z = z*3 + rg. Grid (8, RKS_, 9).
// rg==0 blocks also accumulate sum/sumsq of B (each element seen exactly once
// across the rg==0 sub-grid) -> stp[z][by*8+bx].
// ---------------------------------------------------------------------------
__global__ __launch_bounds__(256) void k_rgemm3(
    const float* __restrict__ lowT, const float* __restrict__ hvT,
    const float* __restrict__ lapd, const float* __restrict__ laph,
    const float* __restrict__ adj, const float* __restrict__ v0,
    const float* __restrict__ S, float* __restrict__ part,
    float* __restrict__ stp) {
  int zz = blockIdx.z;
  int z = zz / 3, rg = zz % 3;
  int col = blockIdx.x * 256 + threadIdx.x;
  int m0 = blockIdx.y * RKC_;
  int m1 = min(N_, m0 + RKC_);
  bool doStats = (rg == 0);
  float sAcc = 0.f, ssAcc = 0.f;
  float acc[16];
#pragma unroll
  for (int r = 0; r < 16; ++r) acc[r] = 0.f;
  if (col < N_) {
    const float* Abase = (z == 1 ? hvT : lowT);
    const float* ap = Abase + (size_t)m0 * BT_ + rg * 16;
    if (z != 1) {
      const float* Bm = z ? laph : lapd;
      const float* bp = Bm + (size_t)m0 * N_ + col;
      int len = m1 - m0;
      int ng = len >> 3;
      float bc[8];
      if (ng > 0) {
#pragma unroll
        for (int u = 0; u < 8; ++u) bc[u] = bp[(size_t)u * N_];
      }
      for (int gi = 0; gi < ng; ++gi) {
        float bn[8];
        bool more = (gi + 1 < ng);
        if (more) {
#pragma unroll
          for (int u = 0; u < 8; ++u) bn[u] = bp[(size_t)(8 + u) * N_];
        }
#pragma unroll
        for (int u = 0; u < 8; ++u) {
          fma16(acc, (const float4*)(ap + (size_t)u * BT_), bc[u]);
          if (doStats) { sAcc += bc[u]; ssAcc = fmaf(bc[u], bc[u], ssAcc); }
        }
        ap += (size_t)8 * BT_;
        bp += (size_t)8 * N_;
        if (more) {
#pragma unroll
          for (int u = 0; u < 8; ++u) bc[u] = bn[u];
        }
      }
      for (int m = m0 + (ng << 3); m < m1; ++m) {
        float bv = *bp;
        fma16(acc, (const float4*)ap, bv);
        if (doStats) { sAcc += bv; ssAcc = fmaf(bv, bv, ssAcc); }
        ap += BT_;
        bp += N_;
      }
    } else {
      const float* jp = adj + (size_t)m0 * N_ + col;
      int len = m1 - m0;
      int ng = len >> 3;
      float jc[8];
      if (ng > 0) {
#pragma unroll
        for (int u = 0; u < 8; ++u) jc[u] = jp[(size_t)u * N_];
      }
      int m = m0;
      for (int gi = 0; gi < ng; ++gi) {
        float jn[8];
        bool more = (gi + 1 < ng);
        if (more) {
#pragma unroll
          for (int u = 0; u < 8; ++u) jn[u] = jp[(size_t)(8 + u) * N_];
        }
#pragma unroll
        for (int u = 0; u < 8; ++u) {
          float bv = -(v0[m + u] / jc[u]);
          if (m + u == col) bv += S[m + u];
          fma16(acc, (const float4*)(ap + (size_t)u * BT_), bv);
          if (doStats) { sAcc += bv; ssAcc = fmaf(bv, bv, ssAcc); }
        }
        m += 8;
        ap += (size_t)8 * BT_;
        jp += (size_t)8 * N_;
        if (more) {
#pragma unroll
          for (int u = 0; u < 8; ++u) jc[u] = jn[u];
        }
      }
      for (; m < m1; ++m) {
        float bv = -(v0[m] / (*jp));
        if (m == col) bv += S[m];
        fma16(acc, (const float4*)ap, bv);
        if (doStats) { sAcc += bv; ssAcc = fmaf(bv, bv, ssAcc); }
        ap += BT_;
        jp += N_;
      }
    }
    float* pp = part + (((size_t)z * RKS_ + blockIdx.y) * BT_ + rg * 16) * N_ + col;
#pragma unroll
    for (int r = 0; r < 16; ++r) pp[(size_t)r * N_] = acc[r];
  }
  if (doStats) {
    __shared__ float r1[4], r2[4];
    float s = sAcc, ss = ssAcc;
    for (int off = 32; off; off >>= 1) { s += __shfl_down(s, off); ss += __shfl_down(ss, off); }
    if ((threadIdx.x & 63) == 0) { r1[threadIdx.x >> 6] = s; r2[threadIdx.x >> 6] = ss; }
    __syncthreads();
    if (threadIdx.x == 0) {
      float* p = stp + (size_t)z * 1024 + ((size_t)blockIdx.y * 8 + blockIdx.x) * 2;
      p[0] = r1[0] + r1[1] + r1[2] + r1[3];
      p[1] = r2[0] + r2[1] + r2[2] + r2[3];
    }
  }
}

// fused r epilogue -> ALIN + At_lin bf16 (k-octet-major)
__global__ void k_epiR3(const float* __restrict__ part, float* __restrict__ ws,
                        unsigned short* __restrict__ atl) {
  int z = blockIdx.z;
  int n = blockIdx.x * 256 + threadIdx.x;
  int row = blockIdx.y;
  if (n >= KP2) return;
  int arow = z * BT_ + row;
  if (n >= N_) { atl[aidx(arow, n)] = 0; return; }
  const float* base = part + (size_t)z * RKS_ * BT_ * N_;
  float s = 0.f;
  for (int ks = 0; ks < RKS_; ++ks) s += base[((size_t)(ks * BT_ + row)) * N_ + n];
  int statIdx = (z == 0) ? 0 : (z == 1 ? 4 : 2);
  size_t rsOff = (z == 1) ? OFF_RSH : OFF_RSL;
  float mu = ws[OFF_STAT + statIdx], isd = ws[OFF_STAT + statIdx + 1];
  float val = (s - mu * ws[rsOff + row]) * isd;
  ws[OFF_ALIN + (size_t)n * R3_ + arow] = val;
  atl[aidx(arow, n)] = f2bf(val);
}

// ---------------------------------------------------------------------------
// MFMA GEMM, 128-col tiles, fused B-transpose+bf16 from fp32 W[K][Nc];
// A in k-octet-major. 2-step-ahead register pipeline, NAMED slots, ONE barrier
// per step: writeLds(data loaded 2 steps ago) -> barrier -> issue s+2 loads ->
// 18 MFMA. part[ks][144][Nc].
// ---------------------------------------------------------------------------
__global__ __launch_bounds__(256) void k_mfmaW(
    const unsigned short* __restrict__ At, const float* __restrict__ W,
    float* __restrict__ part, int Nc, int Kp, int K, int stepChunk) {
  __shared__ unsigned int lds[2][128][21];
  int tid = threadIdx.x;
  int lane = tid & 63, w = tid >> 6;
  int lr = lane & 15, lo = lane >> 4;
  int colBase = blockIdx.x * 128;
  int stepsTot = Kp / 32;
  int s0 = blockIdx.y * stepChunk;
  int s1 = min(stepsTot, s0 + stepChunk);
  int cg = tid & 31, kr8 = tid >> 5;   // col-group of 4 (0..31), k-pair base (0..7)
  int c0l = 4 * cg;
  bool fullC = (colBase + 128 <= Nc);

  f32x4 acc[18];
#pragma unroll
  for (int mt = 0; mt < 18; ++mt) {
    acc[mt][0] = 0.f; acc[mt][1] = 0.f; acc[mt][2] = 0.f; acc[mt][3] = 0.f;
  }

  // load one step's 4 float4s (h=0: kp=kr8, h=1: kp=kr8+8; rows kA,kB each)
  auto loadStep = [&](int s, float4& r00, float4& r10, float4& r01, float4& r11) {
    int c0 = colBase + c0l;
#pragma unroll
    for (int h = 0; h < 2; ++h) {
      int kp = kr8 + 8 * h;
      int kA = s * 32 + 2 * kp;
      int kB = kA + 1;
      float4 r0 = {0.f, 0.f, 0.f, 0.f}, r1 = {0.f, 0.f, 0.f, 0.f};
      if (fullC) {
        if (kA < K) r0 = *(const float4*)(W + (size_t)kA * Nc + c0);
        if (kB < K) r1 = *(const float4*)(W + (size_t)kB * Nc + c0);
      } else {
        float rr0[4] = {0.f, 0.f, 0.f, 0.f}, rr1[4] = {0.f, 0.f, 0.f, 0.f};
#pragma unroll
        for (int e = 0; e < 4; ++e) {
          if (c0 + e < Nc) {
            if (kA < K) rr0[e] = W[(size_t)kA * Nc + c0 + e];
            if (kB < K) rr1[e] = W[(size_t)kB * Nc + c0 + e];
          }
        }
        r0.x = rr0[0]; r0.y = rr0[1]; r0.z = rr0[2]; r0.w = rr0[3];
        r1.x = rr1[0]; r1.y = rr1[1]; r1.z = rr1[2]; r1.w = rr1[3];
      }
      if (h == 0) { r00 = r0; r10 = r1; } else { r01 = r0; r11 = r1; }
    }
  };

  auto writeLds = [&](int buf, const float4& r00, const float4& r10,
                      const float4& r01, const float4& r11) {
    lds[buf][c0l + 0][kr8] = pk2(r10.x, r00.x);
    lds[buf][c0l + 1][kr8] = pk2(r10.y, r00.y);
    lds[buf][c0l + 2][kr8] = pk2(r10.z, r00.z);
    lds[buf][c0l + 3][kr8] = pk2(r10.w, r00.w);
    lds[buf][c0l + 0][kr8 + 8] = pk2(r11.x, r01.x);
    lds[buf][c0l + 1][kr8 + 8] = pk2(r11.y, r01.y);
    lds[buf][c0l + 2][kr8 + 8] = pk2(r11.z, r01.z);
    lds[buf][c0l + 3][kr8 + 8] = pk2(r11.w, r01.w);
  };

  int lcol0 = w * 32 + lr;
  int lcol1 = w * 32 + 16 + lr;
  auto mfmaStep = [&](int buf, const unsigned short* ap) {
    union { unsigned int u[4]; short8 s8; } b0, b1;
#pragma unroll
    for (int j = 0; j < 4; ++j) {
      b0.u[j] = lds[buf][lcol0][lo * 4 + j];
      b1.u[j] = lds[buf][lcol1][lo * 4 + j];
    }
#pragma unroll
    for (int mt = 0; mt < 9; ++mt) {
      short8 a = *(const short8*)(ap + (size_t)mt * 128);
      acc[mt] = __builtin_amdgcn_mfma_f32_16x16x32_bf16(a, b0.s8, acc[mt], 0, 0, 0);
      acc[9 + mt] = __builtin_amdgcn_mfma_f32_16x16x32_bf16(a, b1.s8, acc[9 + mt], 0, 0, 0);
    }
  };

  float4 A00, A10, A01, A11, B00, B10, B01, B11;
  if (s0 < s1) loadStep(s0, A00, A10, A01, A11);
  if (s0 + 1 < s1) loadStep(s0 + 1, B00, B10, B01, B11);

  const unsigned short* ap = At + ((size_t)(s0 * 4 + lo) * R3_ + lr) * 8;
  const size_t apStep = (size_t)4 * R3_ * 8;
  for (int s = s0; s < s1; s += 2) {
    // even step: buf 0, slot A (regs loaded 2 steps ago -> no HBM wait chain)
    writeLds(0, A00, A10, A01, A11);
    __syncthreads();
    if (s + 2 < s1) loadStep(s + 2, A00, A10, A01, A11);
    mfmaStep(0, ap);
    ap += apStep;
    if (s + 1 < s1) {
      // odd step: buf 1, slot B
      writeLds(1, B00, B10, B01, B11);
      __syncthreads();
      if (s + 3 < s1) loadStep(s + 3, B00, B10, B01, B11);
      mfmaStep(1, ap);
      ap += apStep;
    }
  }

#pragma unroll
  for (int half = 0; half < 2; ++half) {
    int gcol = colBase + w * 32 + half * 16 + lr;
    if (gcol < Nc) {
#pragma unroll
      for (int mt = 0; mt < 9; ++mt) {
        int row = mt * 16 + lo * 4;
        float* pp = part + ((size_t)blockIdx.y * R3_ + row) * Nc + gcol;
        f32x4 a = acc[half * 9 + mt];
        pp[0] = a[0];
        pp[(size_t)Nc] = a[1];
        pp[2 * (size_t)Nc] = a[2];
        pp[3 * (size_t)Nc] = a[3];
      }
    }
  }
}

// ---------------------------------------------------------------------------
// Epilogues
// ---------------------------------------------------------------------------
__global__ void k_minmax(const float* __restrict__ alin, float* __restrict__ mmp) {
  int g = blockIdx.y;
  float mn = 3.4e38f, mx = -3.4e38f;
  for (int i = blockIdx.x * 256 + threadIdx.x; i < N_ * BT_; i += 64 * 256) {
    int n = i / BT_, r = i % BT_;
    float v = alin[(size_t)n * R3_ + g * BT_ + r];
    mn = fminf(mn, v); mx = fmaxf(mx, v);
  }
  __shared__ float rn[4], rx[4];
  for (int off = 32; off; off >>= 1) {
    mn = fminf(mn, __shfl_down(mn, off));
    mx = fmaxf(mx, __shfl_down(mx, off));
  }
  if ((threadIdx.x & 63) == 0) { rn[threadIdx.x >> 6] = mn; rx[threadIdx.x >> 6] = mx; }
  __syncthreads();
  if (threadIdx.x == 0) {
    mn = fminf(fminf(rn[0], rn[1]), fminf(rn[2], rn[3]));
    mx = fmaxf(fmaxf(rx[0], rx[1]), fmaxf(rx[2], rx[3]));
    mmp[(size_t)(g * 64 + blockIdx.x) * 2] = mn;
    mmp[(size_t)(g * 64 + blockIdx.x) * 2 + 1] = mx;
  }
}

__global__ void k_minmax2(float* __restrict__ ws) {
  int g = blockIdx.x;
  int i = threadIdx.x;
  float mn = ws[OFF_MMP + (size_t)(g * 64 + i) * 2];
  float mx = ws[OFF_MMP + (size_t)(g * 64 + i) * 2 + 1];
  for (int off = 32; off; off >>= 1) {
    mn = fminf(mn, __shfl_down(mn, off));
    mx = fmaxf(mx, __shfl_down(mx, off));
  }
  if (i == 0) {
    float denom = fmaxf(mx - mn, 1e-8f);
    float a = 1.f / denom;
    ws[OFF_AB + g * 2] = a;
    ws[OFF_AB + g * 2 + 1] = -mn * a;
  }
}

__global__ void k_colsum(const float* __restrict__ ltw, float* __restrict__ csp) {
  int e = blockIdx.x * 256 + threadIdx.x;
  int ks = blockIdx.y;
  if (e >= EA_) return;
  float s = 0.f;
  for (int n = ks * 125; n < (ks + 1) * 125; ++n) s += ltw[(size_t)n * EA_ + e];
  csp[(size_t)ks * EA_ + e] = s;
}
__global__ void k_colsum2(float* __restrict__ ws) {
  int e = blockIdx.x * 256 + threadIdx.x;
  if (e >= EA_) return;
  float s = 0.f;
  for (int ks = 0; ks < 16; ++ks) s += ws[OFF_CSP + (size_t)ks * EA_ + e];
  ws[OFF_CS + e] = s;
}

__global__ void k_epiLin(const float* __restrict__ part, const float* __restrict__ ltb,
                         float* __restrict__ ws, unsigned short* __restrict__ atq,
                         int ksplit) {
  int e = blockIdx.x * 256 + threadIdx.x;
  int row = blockIdx.y;
  if (e >= KP3) return;
  if (e >= EA_) { atq[aidx(row, e)] = 0; return; }
  float s = 0.f;
  for (int ks = 0; ks < ksplit; ++ks) s += part[((size_t)(ks * R3_ + row)) * EA_ + e];
  int g = row / BT_;
  float a = ws[OFF_AB + g * 2], bb = ws[OFF_AB + g * 2 + 1];
  float val = fmaf(a, s, fmaf(bb, ws[OFF_CS + e], ltb[e]));
  atq[aidx(row, e)] = f2bf(val);
}

__global__ void k_epiQkv(const float* __restrict__ part, const float* __restrict__ qkvb,
                         float* __restrict__ P, int ksplit) {
  int c = blockIdx.x * 256 + threadIdx.x;
  int row = blockIdx.y;
  if (c >= 3 * EA_) return;
  float s = 0.f;
  for (int ks = 0; ks < ksplit; ++ks) s += part[((size_t)(ks * R3_ + row)) * (3 * EA_) + c];
  P[(size_t)row * (3 * EA_) + c] = s + qkvb[c];
}

// attention: waves cover t in parallel (wave-local reductions, one barrier)
__global__ void k_attn(const float* __restrict__ P, unsigned short* __restrict__ atao) {
  int mha = blockIdx.y;
  int s_ = blockIdx.x / (B_ * H_);
  int rem = blockIdx.x % (B_ * H_);
  int b = rem / H_, h = rem % H_;
  const int pq[3] = {0, 1, 2}, pk[3] = {1, 2, 0}, pv[3] = {2, 0, 1};
  const float* qrow = P + ((size_t)(pq[mha] * BT_ + s_ * B_ + b)) * (3 * EA_) + h * HD_;
  __shared__ float sc[T_];
  int w = threadIdx.x >> 6, lane = threadIdx.x & 63;
  for (int t = w; t < T_; t += 4) {
    const float* krow = P + ((size_t)(pk[mha] * BT_ + t * B_ + b)) * (3 * EA_) + EA_ + h * HD_;
    float p = 0.f;
    for (int d = lane; d < HD_; d += 64) p = fmaf(qrow[d], krow[d], p);
    p = waveReduceSum(p);
    if (lane == 0) sc[t] = p * 0.031622776601683794f;
  }
  __syncthreads();
  float a[T_];
  float m = sc[0];
#pragma unroll
  for (int t = 1; t < T_; ++t) m = fmaxf(m, sc[t]);
  float sum = 0.f;
#pragma unroll
  for (int t = 0; t < T_; ++t) { a[t] = expf(sc[t] - m); sum += a[t]; }
  float inv = 1.f / sum;
#pragma unroll
  for (int t = 0; t < T_; ++t) a[t] *= inv;
  int orow = mha * BT_ + s_ * B_ + b;
  for (int d = threadIdx.x; d < HD_; d += 256) {
    float o = 0.f;
#pragma unroll
    for (int t = 0; t < T_; ++t)
      o = fmaf(a[t], P[((size_t)(pv[mha] * BT_ + t * B_ + b)) * (3 * EA_) + 2 * EA_ + h * HD_ + d], o);
    atao[aidx(orow, h * HD_ + d)] = f2bf(o);
  }
  if (h == 0 && threadIdx.x < 8) atao[aidx(orow, EA_ + threadIdx.x)] = 0;
}

__global__ void k_epiAO(const float* __restrict__ part, const float* __restrict__ aob,
                        unsigned short* __restrict__ atll, int ksplit) {
  int c = blockIdx.x * 256 + threadIdx.x;
  int row = blockIdx.y;
  if (c >= KP3) return;
  if (c >= EA_) { atll[aidx(row, c)] = 0; return; }
  float s = 0.f;
  for (int ks = 0; ks < ksplit; ++ks) s += part[((size_t)(ks * R3_ + row)) * EA_ + c];
  atll[aidx(row, c)] = f2bf(s + aob[c]);
}

__global__ void k_epiLL(const float* __restrict__ part, const float* __restrict__ llb,
                        float* __restrict__ o2p, int ksplit) {
  int n = blockIdx.x * 256 + threadIdx.x;
  int row = blockIdx.y;  // t*B+b
  if (n >= N_) return;
  float s = 0.f;
  for (int g = 0; g < 3; ++g)
    for (int ks = 0; ks < ksplit; ++ks)
      s += part[((size_t)(ks * R3_ + g * BT_ + row)) * N_ + n];
  int t = row / B_, b = row % B_;
  o2p[(size_t)b * (T_ * N_) + t * N_ + n] = BETA_ * (s + 3.f * llb[n]);
}

__global__ void k_proj(const float* __restrict__ out4, const float* __restrict__ pw,
                       const float* __restrict__ pb, float* __restrict__ outp) {
  int i = blockIdx.x * 256 + threadIdx.x;
  if (i >= BTN_) return;
  int b = i / (T_ * N_);
  int t = (i / N_) % T_;
  int n = i % N_;
  float acc = pb[t];
  for (int t2 = 0; t2 < T_; ++t2) {
    const float* o = out4 + ((size_t)(b * T_ + t2) * N_ + n) * D_;
#pragma unroll
    for (int d = 0; d < D_; ++d) acc = fmaf(o[d], pw[(t2 * D_ + d) * T_ + t], acc);
  }
  outp[i] = acc;
}

__global__ void k_p2(const float* __restrict__ o2p, const float* __restrict__ p2w,
                     const float* __restrict__ p2b, float* __restrict__ o2f) {
  int i = blockIdx.x * 256 + threadIdx.x;
  if (i >= BTN_) return;
  int b = i / (T_ * N_);
  int t = (i / N_) % T_;
  int n = i % N_;
  float acc = p2b[t];
  const float* src = o2p + (size_t)b * (T_ * N_) + (size_t)n * T_;
#pragma unroll
  for (int c = 0; c < T_; ++c) acc = fmaf(src[c], p2w[c * T_ + t], acc);
  o2f[i] = acc;
}

// fused: out3 write + f-normalization -> bf16 padded rows g1b/g2b [8000][32]
__global__ void k_fng(const float* __restrict__ outp, const float* __restrict__ o2f,
                      float* __restrict__ dout, unsigned short* __restrict__ g1b,
                      unsigned short* __restrict__ g2b) {
  int r = blockIdx.x * 256 + threadIdx.x;
  if (r >= B_ * N_) return;
  int b = r / N_, n = r % N_;
  float v1[T_], v2[T_];
  float s1 = 0.f, s2 = 0.f;
#pragma unroll
  for (int t = 0; t < T_; ++t) {
    size_t idx = (size_t)b * T_ * N_ + (size_t)t * N_ + n;
    v1[t] = outp[idx];
    v2[t] = o2f[idx];
    dout[idx] = v1[t] + v2[t];
    s1 = fmaf(v1[t], v1[t], s1);
    s2 = fmaf(v2[t], v2[t], s2);
  }
  float n1 = fmaxf(sqrtf(s1), 1e-12f), n2 = fmaxf(sqrtf(s2), 1e-12f);
  float i1 = 10.f / n1, i2 = 1.f / n2;
  unsigned short q[32], z[32];
#pragma unroll
  for (int t = 0; t < T_; ++t) { q[t] = f2bf(v1[t] * i1); z[t] = f2bf(v2[t] * i2); }
#pragma unroll
  for (int t = T_; t < 32; ++t) { q[t] = 0; z[t] = 0; }
  short8* qd = (short8*)(g1b + (size_t)r * 32);
  short8* zd = (short8*)(g2b + (size_t)r * 32);
#pragma unroll
  for (int c = 0; c < 4; ++c) {
    short8 pv, pz;
#pragma unroll
    for (int e = 0; e < 8; ++e) { pv[e] = (short)q[c * 8 + e]; pz[e] = (short)z[c * 8 + e]; }
    qd[c] = pv;
    zd[c] = pz;
  }
}

// MFMA logsumexp: per block 16 q-rows; 16 j-slices (4 waves x grid.y=4)
__global__ __launch_bounds__(256) void k_lsemf(const unsigned short* __restrict__ g1b,
                                               const unsigned short* __restrict__ g2b,
                                               float* __restrict__ psm,
                                               float* __restrict__ psd) {
  int lane = threadIdx.x & 63, w = threadIdx.x >> 6;
  int lr = lane & 15, lo = lane >> 4;
  int i0 = blockIdx.x * 16;
  int slice = blockIdx.y * 4 + w;     // 0..15
  short8 a = *(const short8*)(g1b + (size_t)(i0 + lr) * 32 + lo * 8);
  float sm[4] = {0.f, 0.f, 0.f, 0.f};
  float sd[4] = {0.f, 0.f, 0.f, 0.f};
  for (int t = slice; t < 500; t += 16) {
    int j0 = t * 16;
    short8 b = *(const short8*)(g2b + (size_t)(j0 + lr) * 32 + lo * 8);
    f32x4 acc = {0.f, 0.f, 0.f, 0.f};
    acc = __builtin_amdgcn_mfma_f32_16x16x32_bf16(a, b, acc, 0, 0, 0);
#pragma unroll
    for (int rg = 0; rg < 4; ++rg) {
      float s = acc[rg];
      sm[rg] += __expf(s);
      if (j0 + lr == i0 + lo * 4 + rg) sd[rg] = s;
    }
  }
#pragma unroll
  for (int off = 1; off < 16; off <<= 1) {
#pragma unroll
    for (int rg = 0; rg < 4; ++rg) {
      sm[rg] += __shfl_xor(sm[rg], off);
      sd[rg] += __shfl_xor(sd[rg], off);
    }
  }
  __shared__ float lsm[4][16], lsd[4][16];
  if (lr == 0) {
#pragma unroll
    for (int rg = 0; rg < 4; ++rg) {
      lsm[w][lo * 4 + rg] = sm[rg];
      lsd[w][lo * 4 + rg] = sd[rg];
    }
  }
  __syncthreads();
  if (threadIdx.x < 16) {
    float m = lsm[0][threadIdx.x] + lsm[1][threadIdx.x] + lsm[2][threadIdx.x] + lsm[3][threadIdx.x];
    float d = lsd[0][threadIdx.x] + lsd[1][threadIdx.x] + lsd[2][threadIdx.x] + lsd[3][threadIdx.x];
    psm[(size_t)blockIdx.y * 8000 + i0 + threadIdx.x] = m;
    psd[(size_t)blockIdx.y * 8000 + i0 + threadIdx.x] = d;
  }
}

// fused: combine j-splits + mean + final scalars
__global__ __launch_bounds__(1024) void k_lsefin(const float* __restrict__ psm,
                                                 const float* __restrict__ psd,
                                                 const float* __restrict__ ws,
                                                 float* __restrict__ dout) {
  float acc = 0.f;
  for (int r = threadIdx.x; r < B_ * N_; r += 1024) {
    float sm = psm[r] + psm[8000 + r] + psm[16000 + r] + psm[24000 + r];
    float sd = psd[r] + psd[8000 + r] + psd[16000 + r] + psd[24000 + r];
    acc += sd - logf(sm);
  }
  __shared__ float red[16];
  acc = waveReduceSum(acc);
  if ((threadIdx.x & 63) == 0) red[threadIdx.x >> 6] = acc;
  __syncthreads();
  if (threadIdx.x == 0) {
    float s = 0.f;
    for (int i = 0; i < 16; ++i) s += red[i];
    float closs = -s * (1.f / (B_ * N_));
    dout[BTN_] = ws[OFF_BAL];
    dout[BTN_ + 1] = CW_ * closs;
  }
}

// ---------------------------------------------------------------------------
extern "C" void kernel_launch(void* const* d_in, const int* in_sizes, int n_in,
                              void* d_out, int out_size, void* d_ws, size_t ws_size,
                              hipStream_t stream) {
  const float* x    = (const float*)d_in[0];
  const float* velo = (const float*)d_in[1];
  const float* adj  = (const float*)d_in[2];
  const float* lapd = (const float*)d_in[3];
  const float* laph = (const float*)d_in[4];
  const float* sw   = (const float*)d_in[5];
  const float* sb   = (const float*)d_in[6];
  const float* gw   = (const float*)d_in[7];
  const float* ew1  = (const float*)d_in[8];
  const float* eb1  = (const float*)d_in[9];
  const float* ew2  = (const float*)d_in[10];
  const float* eb2  = (const float*)d_in[11];
  const float* pw   = (const float*)d_in[12];
  const float* pb   = (const float*)d_in[13];
  const float* ltw  = (const float*)d_in[14];
  const float* ltb  = (const float*)d_in[15];
  const float* qkvw = (const float*)d_in[16];
  const float* qkvb = (const float*)d_in[17];
  const float* aow  = (const float*)d_in[18];
  const float* aob  = (const float*)d_in[19];
  const float* llw  = (const float*)d_in[20];
  const float* llb  = (const float*)d_in[21];
  const float* p2w  = (const float*)d_in[22];
  const float* p2b  = (const float*)d_in[23];
  float* ws = (float*)d_ws;
  float* dout = (float*)d_out;
  const float* v0 = velo;  // velo[0,0,:]
  float* part = ws + OFF_PART;
  unsigned short* atLin = (unsigned short*)(ws + OFF_AT_LIN);
  unsigned short* atQ   = (unsigned short*)(ws + OFF_AT_Q);
  unsigned short* atAO  = (unsigned short*)(ws + OFF_AT_AO);
  unsigned short* atLL  = (unsigned short*)(ws + OFF_AT_LL);
  unsigned short* g1b   = (unsigned short*)(ws + OFF_G1B);
  unsigned short* g2b   = (unsigned short*)(ws + OFF_G2B);
  dim3 b256(256);

  k_init<<<dim3(1), dim3(64), 0, stream>>>(ws);

  k_start<<<dim3((BTN_ * D_ + 255) / 256), b256, 0, stream>>>(x, sw, sb, ws + OFF_OUT4);

  for (int l = 0; l < L_; ++l) {
    k_feat<<<dim3(B_ * D_), b256, 0, stream>>>(ws + OFF_OUT4, ws + OFF_FEAT);
    k_gate<<<dim3(1), dim3(64), 0, stream>>>(ws + OFF_FEAT, gw, ws, l);
    k_expert<<<dim3((T_ * N_ + 255) / 256, B_), b256, 0, stream>>>(ws + OFF_OUT4, ew1, eb1, ew2, eb2, ws, l);
  }

  k_wavelet<<<dim3((BTN_ + 255) / 256), b256, 0, stream>>>(x, velo, ws + OFF_LOWT, ws + OFF_HVT);
  k_rowsum<<<dim3(2 * BT_), b256, 0, stream>>>(ws + OFF_LOWT, ws + OFF_HVT, ws);
  k_S<<<dim3(N_), b256, 0, stream>>>(adj, v0, ws + OFF_S);

  // fused r1/r2/r3 GEMMs (with in-line B stats) then stats reduce + epilogue
  k_rgemm3<<<dim3(8, RKS_, 9), b256, 0, stream>>>(ws + OFF_LOWT, ws + OFF_HVT, lapd, laph,
                                                  adj, v0, ws + OFF_S, part, ws + OFF_STP);
  k_stats2<<<dim3(3), b256, 0, stream>>>(ws + OFF_STP, ws + OFF_STAT);
  k_epiR3<<<dim3(8, 48, 3), b256, 0, stream>>>(part, ws, atLin);

  k_minmax<<<dim3(64, 3), b256, 0, stream>>>(ws + OFF_ALIN, ws + OFF_MMP);
  k_minmax2<<<dim3(3), dim3(64), 0, stream>>>(ws);
  k_colsum<<<dim3(12, 16), b256, 0, stream>>>(ltw, ws + OFF_CSP);
  k_colsum2<<<dim3(12), b256, 0, stream>>>(ws);

  // lin (MFMA, 128-col tiles, 2-deep pipeline): 16 splits x 4 steps (63 steps)
  k_mfmaW<<<dim3(24, 16), b256, 0, stream>>>(atLin, ltw, part, EA_, KP2, N_, 4);
  k_epiLin<<<dim3(12, 144), b256, 0, stream>>>(part, ltb, ws, atQ, 16);

  // qkv (MFMA, 128-col tiles, 2-deep pipeline): 8 splits x 12 steps (94 steps)
  k_mfmaW<<<dim3(71, 8), b256, 0, stream>>>(atQ, qkvw, part, 3 * EA_, KP3, EA_, 12);
  k_epiQkv<<<dim3(36, 144), b256, 0, stream>>>(part, qkvb, ws + OFF_P, 8);

  // attention
  k_attn<<<dim3(T_ * B_ * H_, 3), b256, 0, stream>>>(ws + OFF_P, atAO);

  // attn-out (MFMA, 128-col tiles, 2-deep pipeline): 16 splits x 6 steps
  k_mfmaW<<<dim3(24, 16), b256, 0, stream>>>(atAO, aow, part, EA_, KP3, EA_, 6);
  k_epiAO<<<dim3(12, 144), b256, 0, stream>>>(part, aob, atLL, 16);

  // ll (MFMA, 128-col tiles, 2-deep pipeline): 20 splits x 5 steps
  k_mfmaW<<<dim3(16, 20), b256, 0, stream>>>(atLL, llw, part, N_, KP3, EA_, 5);
  k_epiLL<<<dim3(8, 48), b256, 0, stream>>>(part, llb, ws + OFF_O2P, 20);

  k_proj<<<dim3((BTN_ + 255) / 256), b256, 0, stream>>>(ws + OFF_OUT4, pw, pb, ws + OFF_OUTP);
  k_p2<<<dim3((BTN_ + 255) / 256), b256, 0, stream>>>(ws + OFF_O2P, p2w, p2b, ws + OFF_O2F);

  // fused out3 + fnorm (writes dout body + bf16 g1b/g2b)
  k_fng<<<dim3((B_ * N_ + 255) / 256), b256, 0, stream>>>(ws + OFF_OUTP, ws + OFF_O2F, dout, g1b, g2b);

  // MFMA logsumexp; psm/psd partials live in `part`
  k_lsemf<<<dim3(500, 4), b256, 0, stream>>>(g1b, g2b, part, part + 32000);
  k_lsefin<<<dim3(1), dim3(1024), 0, stream>>>(part, part + 32000, ws, dout);
}

// Round 22
// 481.868 us; speedup vs baseline: 1.1490x; 1.0423x over previous
//
#include <hip/hip_runtime.h>
#include <math.h>

// ---------------------------------------------------------------------------
// Model constants
// ---------------------------------------------------------------------------
namespace {
constexpr int B_ = 4, T_ = 12, N_ = 2000, D_ = 16, FF_ = 64, E_ = 4, L_ = 2;
constexpr int EA_ = 3000, H_ = 3, HD_ = EA_ / H_;   // 1000
constexpr int BT_ = B_ * T_;                         // 48
constexpr int R3_ = 3 * BT_;                         // 144
constexpr long long NN_ = (long long)N_ * N_;        // 4,000,000
constexpr int BTN_ = B_ * T_ * N_;                   // 96,000
constexpr float BETA_ = 0.01f, CW_ = 0.001f;
constexpr int RKS_ = 20;                             // r-GEMM split-K (fused x3)
constexpr int RKC_ = 100;                            // r-GEMM k-chunk
constexpr int KP3 = 3008;                            // K=3000 padded to 32
constexpr int KP2 = 2016;                            // K=2000 padded to 32

// ---------------------------------------------------------------------------
// Workspace layout (float offsets)
// ---------------------------------------------------------------------------
constexpr size_t OFF_OUT4 = 0;                                   // [B,T,N,D]
constexpr size_t OFF_LOWT = OFF_OUT4 + (size_t)BTN_ * D_;        // lowT^T [N][48]
constexpr size_t OFF_HVT  = OFF_LOWT + BTN_;                     // highV^T [N][48]
constexpr size_t OFF_ALIN = OFF_HVT + BTN_;                      // r^T [N][144]
constexpr size_t OFF_RT   = OFF_ALIN + (size_t)N_ * R3_;         // (unused, kept)
constexpr size_t OFF_P    = OFF_RT + (size_t)EA_ * R3_;          // P [144][9000]
constexpr size_t OFF_AOT  = OFF_P + (size_t)R3_ * 3 * EA_;       // (unused, kept)
constexpr size_t OFF_OT   = OFF_AOT + (size_t)EA_ * R3_;         // (unused, kept)
constexpr size_t OFF_O2P  = OFF_OT + (size_t)EA_ * R3_;          // out2 pre-p2 [B][T*N]
constexpr size_t OFF_OUTP = OFF_O2P + BTN_;                      // (spare)
constexpr size_t OFF_O2F  = OFF_OUTP + BTN_;                     // (spare)
constexpr size_t OFF_LI   = OFF_O2F + BTN_;                      // (spare)
constexpr size_t OFF_S    = OFF_LI + 8000;                       // G row sums [2000]
constexpr size_t OFF_RSL  = OFF_S + 2000;
constexpr size_t OFF_RSH  = OFF_RSL + 48;
constexpr size_t OFF_STP  = OFF_RSH + 48;
constexpr size_t OFF_STAT = OFF_STP + 3072;
constexpr size_t OFF_MMP  = OFF_STAT + 8;
constexpr size_t OFF_AB   = OFF_MMP + 384;
constexpr size_t OFF_CSP  = OFF_AB + 8;
constexpr size_t OFF_CS   = OFF_CSP + 48000;
constexpr size_t OFF_FEAT = OFF_CS + 3000;
constexpr size_t OFF_GATE = OFF_FEAT + 64;
constexpr size_t OFF_BAL  = OFF_GATE + 16;
constexpr size_t OFF_PART = ((OFF_BAL + 1 + 255) & ~(size_t)255); // split-K partials
constexpr size_t PARTCAP  = 13000000;                             // cap (floats)
// bf16 A-operand regions, k-octet-major [Kp/8][144][8] (sizes in floats)
constexpr size_t OFF_AT_LIN= OFF_PART + PARTCAP;                  // [KP2/8][144][8]
constexpr size_t OFF_AT_Q  = OFF_AT_LIN + (size_t)R3_ * KP2 / 2;
constexpr size_t OFF_AT_AO = OFF_AT_Q + (size_t)R3_ * KP3 / 2;
constexpr size_t OFF_AT_LL = OFF_AT_AO + (size_t)R3_ * KP3 / 2;
constexpr size_t OFF_G1B   = OFF_AT_LL + (size_t)R3_ * KP3 / 2;   // f1 bf16 [8000][32]
constexpr size_t OFF_G2B   = OFF_G1B + 128000;                    // f2 bf16 [8000][32]
} // namespace

typedef __attribute__((ext_vector_type(8))) short short8;
typedef __attribute__((ext_vector_type(4))) float f32x4;

// ---------------------------------------------------------------------------
// Helpers
// ---------------------------------------------------------------------------
__device__ __forceinline__ float waveReduceSum(float v) {
  for (int off = 32; off; off >>= 1) v += __shfl_down(v, off);
  return v;
}

__device__ __forceinline__ unsigned short f2bf(float x) {  // RNE fp32->bf16
  unsigned int u = __float_as_uint(x);
  unsigned int r = (u + 0x7FFFu + ((u >> 16) & 1u)) >> 16;
  return (unsigned short)r;
}

// k-octet-major A index: (row, k) -> [(k/8)][row][k%8]
__device__ __forceinline__ size_t aidx(int row, int k) {
  return ((size_t)(k >> 3) * R3_ + row) * 8 + (k & 7);
}

__device__ __forceinline__ void fma16(float* __restrict__ acc,
                                      const float4* __restrict__ a4, float bv) {
#pragma unroll
  for (int r4 = 0; r4 < 4; ++r4) {
    float4 av = a4[r4];
    acc[r4 * 4 + 0] = fmaf(av.x, bv, acc[r4 * 4 + 0]);
    acc[r4 * 4 + 1] = fmaf(av.y, bv, acc[r4 * 4 + 1]);
    acc[r4 * 4 + 2] = fmaf(av.z, bv, acc[r4 * 4 + 2]);
    acc[r4 * 4 + 3] = fmaf(av.w, bv, acc[r4 * 4 + 3]);
  }
}

// ---------------------------------------------------------------------------
__global__ void k_init(float* ws) {
  if (threadIdx.x == 0) ws[OFF_BAL] = 0.f;
}

__global__ void k_start(const float* __restrict__ x, const float* __restrict__ sw,
                        const float* __restrict__ sb, float* __restrict__ out4) {
  int i = blockIdx.x * 256 + threadIdx.x;
  if (i >= BTN_ * D_) return;
  int d = i & 15;
  out4[i] = fmaf(x[i >> 4], sw[d], sb[d]);
}

__global__ void k_feat(const float* __restrict__ out4, float* __restrict__ feat) {
  int b = blockIdx.x >> 4, d = blockIdx.x & 15;
  float s = 0.f;
  for (int tn = threadIdx.x; tn < T_ * N_; tn += 256)
    s += out4[((size_t)b * T_ * N_ + tn) * D_ + d];
  __shared__ float red[4];
  s = waveReduceSum(s);
  if ((threadIdx.x & 63) == 0) red[threadIdx.x >> 6] = s;
  __syncthreads();
  if (threadIdx.x == 0)
    feat[blockIdx.x] = (red[0] + red[1] + red[2] + red[3]) * (1.f / (T_ * N_));
}

__global__ void k_gate(const float* __restrict__ feat, const float* __restrict__ gw,
                       float* __restrict__ ws, int l) {
  __shared__ float lg[B_ * E_];
  int tid = threadIdx.x;
  if (tid < B_ * E_) {
    int b = tid >> 2, e = tid & 3;
    float s = 0.f;
    for (int d = 0; d < D_; ++d) s = fmaf(feat[b * D_ + d], gw[(l * D_ + d) * E_ + e], s);
    lg[tid] = s;
  }
  __syncthreads();
  if (tid == 0) {
    float* gates = ws + OFF_GATE;
    float imp[E_] = {0, 0, 0, 0}, load[E_] = {0, 0, 0, 0};
    for (int i = 0; i < B_ * E_; ++i) gates[i] = 0.f;
    for (int b = 0; b < B_; ++b) {
      const float* lb = lg + b * E_;
      int i1 = 0; float v1 = lb[0];
      for (int e = 1; e < E_; ++e) if (lb[e] > v1) { v1 = lb[e]; i1 = e; }
      int i2 = -1; float v2 = -1e30f;
      for (int e = 0; e < E_; ++e) { if (e == i1) continue; if (lb[e] > v2) { v2 = lb[e]; i2 = e; } }
      float e2 = expf(v2 - v1);
      float den = 1.f + e2;
      float g1 = 1.f / den, g2 = e2 / den;
      gates[b * E_ + i1] = g1; gates[b * E_ + i2] = g2;
      imp[i1] += g1; imp[i2] += g2; load[i1] += 1.f; load[i2] += 1.f;
    }
    float bal = 0.f;
    float m = 0.f; for (int e = 0; e < E_; ++e) m += imp[e]; m *= 0.25f;
    float v = 0.f; for (int e = 0; e < E_; ++e) { float d = imp[e] - m; v += d * d; } v *= 0.25f;
    bal += v / (m * m + 1e-10f);
    m = 0.f; for (int e = 0; e < E_; ++e) m += load[e]; m *= 0.25f;
    v = 0.f; for (int e = 0; e < E_; ++e) { float d = load[e] - m; v += d * d; } v *= 0.25f;
    bal += v / (m * m + 1e-10f);
    ws[OFF_BAL] += bal;
  }
}

// MoE expert apply; gelu via sigmoid identity
__global__ void k_expert(float* __restrict__ out4, const float* __restrict__ w1,
                         const float* __restrict__ b1, const float* __restrict__ w2,
                         const float* __restrict__ b2, const float* __restrict__ ws, int l) {
  int b = blockIdx.y;
  int tn = blockIdx.x * 256 + threadIdx.x;
  if (tn >= T_ * N_) return;
  float* row = out4 + ((size_t)b * T_ * N_ + tn) * D_;
  float r[D_], acc[D_];
#pragma unroll
  for (int d = 0; d < D_; ++d) { r[d] = row[d]; acc[d] = r[d]; }
  const float* gates = ws + OFF_GATE;
  for (int e = 0; e < E_; ++e) {
    float g = gates[b * E_ + e];
    if (g <= 0.f) continue;
    const float* W1 = w1 + (size_t)(l * E_ + e) * D_ * FF_;
    const float* B1 = b1 + (size_t)(l * E_ + e) * FF_;
    const float* W2 = w2 + (size_t)(l * E_ + e) * FF_ * D_;
    const float* B2 = b2 + (size_t)(l * E_ + e) * D_;
#pragma unroll 4
    for (int f = 0; f < FF_; ++f) {
      float p = B1[f];
#pragma unroll
      for (int d = 0; d < D_; ++d) p = fmaf(r[d], W1[d * FF_ + f], p);
      float c2 = 1.5957691216057308f * (p + 0.044715f * p * p * p);
      float e1 = __expf(-c2);
      float hv = p * __builtin_amdgcn_rcpf(1.f + e1);
      float gh = g * hv;
#pragma unroll
      for (int d = 0; d < D_; ++d) acc[d] = fmaf(gh, W2[f * D_ + d], acc[d]);
    }
#pragma unroll
    for (int d = 0; d < D_; ++d) acc[d] = fmaf(g, B2[d], acc[d]);
  }
#pragma unroll
  for (int d = 0; d < D_; ++d) row[d] = acc[d];
}

__global__ void k_wavelet(const float* __restrict__ x, const float* __restrict__ velo,
                          float* __restrict__ lowT, float* __restrict__ hvT) {
  int i = blockIdx.x * 256 + threadIdx.x;
  if (i >= BTN_) return;
  int b = i / (T_ * N_);
  int t = (i / N_) % T_;
  int n = i % N_;
  int ip = b * T_ * N_ + ((t + T_ - 1) % T_) * N_ + n;
  int row = t * B_ + b;
  lowT[(size_t)n * BT_ + row] = 0.5f * (x[i] + x[ip]);
  hvT[(size_t)n * BT_ + row] = 0.5f * (velo[i] - velo[ip]);
}

__global__ void k_rowsum(const float* __restrict__ lowT, const float* __restrict__ hvT,
                         float* __restrict__ ws) {
  int which = blockIdx.x / BT_;
  int row = blockIdx.x % BT_;
  const float* M = which ? hvT : lowT;
  float s = 0.f;
  for (int n = threadIdx.x; n < N_; n += 256) s += M[(size_t)n * BT_ + row];
  __shared__ float red[4];
  s = waveReduceSum(s);
  if ((threadIdx.x & 63) == 0) red[threadIdx.x >> 6] = s;
  __syncthreads();
  if (threadIdx.x == 0) ws[(which ? OFF_RSH : OFF_RSL) + row] = red[0] + red[1] + red[2] + red[3];
}

__global__ void k_S(const float* __restrict__ adj, const float* __restrict__ v0,
                    float* __restrict__ S) {
  int m = blockIdx.x;
  float vm = v0[m];
  const float* a = adj + (size_t)m * N_;
  float s = 0.f;
  for (int n = threadIdx.x; n < N_; n += 256) s += vm / a[n];
  __shared__ float red[4];
  s = waveReduceSum(s);
  if ((threadIdx.x & 63) == 0) red[threadIdx.x >> 6] = s;
  __syncthreads();
  if (threadIdx.x == 0) S[m] = red[0] + red[1] + red[2] + red[3];
}

// combine fused-stats partials (160 per matrix) -> {mu, 1/std}
__global__ void k_stats2(const float* __restrict__ stp, float* __restrict__ stat) {
  int z = blockIdx.x;
  const float* part = stp + (size_t)z * 1024;
  float s = 0.f, ss = 0.f;
  for (int i = threadIdx.x; i < 160; i += 256) { s += part[i * 2]; ss += part[i * 2 + 1]; }
  __shared__ float r1[4], r2[4];
  for (int off = 32; off; off >>= 1) { s += __shfl_down(s, off); ss += __shfl_down(ss, off); }
  if ((threadIdx.x & 63) == 0) { r1[threadIdx.x >> 6] = s; r2[threadIdx.x >> 6] = ss; }
  __syncthreads();
  if (threadIdx.x == 0) {
    float su = r1[0] + r1[1] + r1[2] + r1[3];
    float sq = r2[0] + r2[1] + r2[2] + r2[3];
    float mu = su * (1.f / (float)NN_);
    float var = sq * (1.f / (float)NN_) - mu * mu;
    stat[2 * z] = mu;
    stat[2 * z + 1] = 1.f / sqrtf(var);
  }
}

// ---------------------------------------------------------------------------
// Fused r-GEMMs, 16-row accumulators: blockIdx.z = z*3 + rg. Grid (8, RKS_, 9).
// rg==0 blocks also accumulate sum/sumsq of B -> stp[z][by*8+bx].
// ---------------------------------------------------------------------------
__global__ __launch_bounds__(256) void k_rgemm3(
    const float* __restrict__ lowT, const float* __restrict__ hvT,
    const float* __restrict__ lapd, const float* __restrict__ laph,
    const float* __restrict__ adj, const float* __restrict__ v0,
    const float* __restrict__ S, float* __restrict__ part,
    float* __restrict__ stp) {
  int zz = blockIdx.z;
  int z = zz / 3, rg = zz % 3;
  int col = blockIdx.x * 256 + threadIdx.x;
  int m0 = blockIdx.y * RKC_;
  int m1 = min(N_, m0 + RKC_);
  bool doStats = (rg == 0);
  float sAcc = 0.f, ssAcc = 0.f;
  float acc[16];
#pragma unroll
  for (int r = 0; r < 16; ++r) acc[r] = 0.f;
  if (col < N_) {
    const float* Abase = (z == 1 ? hvT : lowT);
    const float* ap = Abase + (size_t)m0 * BT_ + rg * 16;
    if (z != 1) {
      const float* Bm = z ? laph : lapd;
      const float* bp = Bm + (size_t)m0 * N_ + col;
      int len = m1 - m0;
      int ng = len >> 3;
      float bc[8];
      if (ng > 0) {
#pragma unroll
        for (int u = 0; u < 8; ++u) bc[u] = bp[(size_t)u * N_];
      }
      for (int gi = 0; gi < ng; ++gi) {
        float bn[8];
        bool more = (gi + 1 < ng);
        if (more) {
#pragma unroll
          for (int u = 0; u < 8; ++u) bn[u] = bp[(size_t)(8 + u) * N_];
        }
#pragma unroll
        for (int u = 0; u < 8; ++u) {
          fma16(acc, (const float4*)(ap + (size_t)u * BT_), bc[u]);
          if (doStats) { sAcc += bc[u]; ssAcc = fmaf(bc[u], bc[u], ssAcc); }
        }
        ap += (size_t)8 * BT_;
        bp += (size_t)8 * N_;
        if (more) {
#pragma unroll
          for (int u = 0; u < 8; ++u) bc[u] = bn[u];
        }
      }
      for (int m = m0 + (ng << 3); m < m1; ++m) {
        float bv = *bp;
        fma16(acc, (const float4*)ap, bv);
        if (doStats) { sAcc += bv; ssAcc = fmaf(bv, bv, ssAcc); }
        ap += BT_;
        bp += N_;
      }
    } else {
      const float* jp = adj + (size_t)m0 * N_ + col;
      int len = m1 - m0;
      int ng = len >> 3;
      float jc[8];
      if (ng > 0) {
#pragma unroll
        for (int u = 0; u < 8; ++u) jc[u] = jp[(size_t)u * N_];
      }
      int m = m0;
      for (int gi = 0; gi < ng; ++gi) {
        float jn[8];
        bool more = (gi + 1 < ng);
        if (more) {
#pragma unroll
          for (int u = 0; u < 8; ++u) jn[u] = jp[(size_t)(8 + u) * N_];
        }
#pragma unroll
        for (int u = 0; u < 8; ++u) {
          float bv = -(v0[m + u] / jc[u]);
          if (m + u == col) bv += S[m + u];
          fma16(acc, (const float4*)(ap + (size_t)u * BT_), bv);
          if (doStats) { sAcc += bv; ssAcc = fmaf(bv, bv, ssAcc); }
        }
        m += 8;
        ap += (size_t)8 * BT_;
        jp += (size_t)8 * N_;
        if (more) {
#pragma unroll
          for (int u = 0; u < 8; ++u) jc[u] = jn[u];
        }
      }
      for (; m < m1; ++m) {
        float bv = -(v0[m] / (*jp));
        if (m == col) bv += S[m];
        fma16(acc, (const float4*)ap, bv);
        if (doStats) { sAcc += bv; ssAcc = fmaf(bv, bv, ssAcc); }
        ap += BT_;
        jp += N_;
      }
    }
    float* pp = part + (((size_t)z * RKS_ + blockIdx.y) * BT_ + rg * 16) * N_ + col;
#pragma unroll
    for (int r = 0; r < 16; ++r) pp[(size_t)r * N_] = acc[r];
  }
  if (doStats) {
    __shared__ float r1[4], r2[4];
    float s = sAcc, ss = ssAcc;
    for (int off = 32; off; off >>= 1) { s += __shfl_down(s, off); ss += __shfl_down(ss, off); }
    if ((threadIdx.x & 63) == 0) { r1[threadIdx.x >> 6] = s; r2[threadIdx.x >> 6] = ss; }
    __syncthreads();
    if (threadIdx.x == 0) {
      float* p = stp + (size_t)z * 1024 + ((size_t)blockIdx.y * 8 + blockIdx.x) * 2;
      p[0] = r1[0] + r1[1] + r1[2] + r1[3];
      p[1] = r2[0] + r2[1] + r2[2] + r2[3];
    }
  }
}

// fused r epilogue -> ALIN + At_lin bf16 (k-octet-major)
__global__ void k_epiR3(const float* __restrict__ part, float* __restrict__ ws,
                        unsigned short* __restrict__ atl) {
  int z = blockIdx.z;
  int n = blockIdx.x * 256 + threadIdx.x;
  int row = blockIdx.y;
  if (n >= KP2) return;
  int arow = z * BT_ + row;
  if (n >= N_) { atl[aidx(arow, n)] = 0; return; }
  const float* base = part + (size_t)z * RKS_ * BT_ * N_;
  float s = 0.f;
  for (int ks = 0; ks < RKS_; ++ks) s += base[((size_t)(ks * BT_ + row)) * N_ + n];
  int statIdx = (z == 0) ? 0 : (z == 1 ? 4 : 2);
  size_t rsOff = (z == 1) ? OFF_RSH : OFF_RSL;
  float mu = ws[OFF_STAT + statIdx], isd = ws[OFF_STAT + statIdx + 1];
  float val = (s - mu * ws[rsOff + row]) * isd;
  ws[OFF_ALIN + (size_t)n * R3_ + arow] = val;
  atl[aidx(arow, n)] = f2bf(val);
}

// ---------------------------------------------------------------------------
// MFMA GEMM, 64-col tiles (r15-proven): fused B-transpose+bf16 from fp32
// W[K][Nc]; A in k-octet-major. One barrier per step. part[ks][144][Nc].
// ---------------------------------------------------------------------------
__global__ __launch_bounds__(256) void k_mfmaW(
    const unsigned short* __restrict__ At, const float* __restrict__ W,
    float* __restrict__ part, int Nc, int Kp, int K, int stepChunk) {
  __shared__ unsigned int lds[2][64][21];
  int tid = threadIdx.x;
  int lane = tid & 63, w = tid >> 6;
  int lr = lane & 15, lo = lane >> 4;
  int colBase = blockIdx.x * 64;
  int gcol = colBase + w * 16 + lr;
  int stepsTot = Kp / 32;
  int s0 = blockIdx.y * stepChunk;
  int s1 = min(stepsTot, s0 + stepChunk);
  int cg = tid & 15, kr2 = tid >> 4;
  int c0l = 4 * cg;
  bool fullC = (colBase + 64 <= Nc);

  f32x4 acc[9];
#pragma unroll
  for (int mt = 0; mt < 9; ++mt) {
    acc[mt][0] = 0.f; acc[mt][1] = 0.f; acc[mt][2] = 0.f; acc[mt][3] = 0.f;
  }

  auto stage = [&](int s, int buf) {
    int kA = s * 32 + 2 * kr2;
    int kB = kA + 1;
    float4 r0 = {0.f, 0.f, 0.f, 0.f}, r1 = {0.f, 0.f, 0.f, 0.f};
    int c0 = colBase + c0l;
    if (fullC) {
      if (kA < K) r0 = *(const float4*)(W + (size_t)kA * Nc + c0);
      if (kB < K) r1 = *(const float4*)(W + (size_t)kB * Nc + c0);
    } else {
      float rr0[4] = {0.f, 0.f, 0.f, 0.f}, rr1[4] = {0.f, 0.f, 0.f, 0.f};
#pragma unroll
      for (int e = 0; e < 4; ++e) {
        if (c0 + e < Nc) {
          if (kA < K) rr0[e] = W[(size_t)kA * Nc + c0 + e];
          if (kB < K) rr1[e] = W[(size_t)kB * Nc + c0 + e];
        }
      }
      r0.x = rr0[0]; r0.y = rr0[1]; r0.z = rr0[2]; r0.w = rr0[3];
      r1.x = rr1[0]; r1.y = rr1[1]; r1.z = rr1[2]; r1.w = rr1[3];
    }
    lds[buf][c0l + 0][kr2] = ((unsigned int)f2bf(r1.x) << 16) | f2bf(r0.x);
    lds[buf][c0l + 1][kr2] = ((unsigned int)f2bf(r1.y) << 16) | f2bf(r0.y);
    lds[buf][c0l + 2][kr2] = ((unsigned int)f2bf(r1.z) << 16) | f2bf(r0.z);
    lds[buf][c0l + 3][kr2] = ((unsigned int)f2bf(r1.w) << 16) | f2bf(r0.w);
  };

  if (s0 < s1) stage(s0, 0);
  __syncthreads();

  // A base: k-octet (s*4 + lo), row lr; advance 4*144*8 ushorts per step
  const unsigned short* ap = At + ((size_t)(s0 * 4 + lo) * R3_ + lr) * 8;
  int lcol = w * 16 + lr;
  for (int s = s0; s < s1; ++s) {
    int buf = (s - s0) & 1;
    union { unsigned int u[4]; short8 s8; } bu;
#pragma unroll
    for (int j = 0; j < 4; ++j) bu.u[j] = lds[buf][lcol][lo * 4 + j];
    short8 b = bu.s8;
#pragma unroll
    for (int mt = 0; mt < 9; ++mt) {
      short8 a = *(const short8*)(ap + (size_t)mt * 128);
      acc[mt] = __builtin_amdgcn_mfma_f32_16x16x32_bf16(a, b, acc[mt], 0, 0, 0);
    }
    if (s + 1 < s1) stage(s + 1, buf ^ 1);
    __syncthreads();
    ap += (size_t)4 * R3_ * 8;
  }

  if (gcol < Nc) {
#pragma unroll
    for (int mt = 0; mt < 9; ++mt) {
      int row = mt * 16 + lo * 4;
      float* pp = part + ((size_t)blockIdx.y * R3_ + row) * Nc + gcol;
      pp[0] = acc[mt][0];
      pp[(size_t)Nc] = acc[mt][1];
      pp[2 * (size_t)Nc] = acc[mt][2];
      pp[3 * (size_t)Nc] = acc[mt][3];
    }
  }
}

// ---------------------------------------------------------------------------
// MFMA GEMM, 128-col tiles (r19-proven, for the wide qkv GEMM only).
// 18 MFMA per step per wave, one barrier per step. part[ks][144][Nc].
// ---------------------------------------------------------------------------
__global__ __launch_bounds__(256) void k_mfmaWq(
    const unsigned short* __restrict__ At, const float* __restrict__ W,
    float* __restrict__ part, int Nc, int Kp, int K, int stepChunk) {
  __shared__ unsigned int lds[2][128][21];
  int tid = threadIdx.x;
  int lane = tid & 63, w = tid >> 6;
  int lr = lane & 15, lo = lane >> 4;
  int colBase = blockIdx.x * 128;
  int stepsTot = Kp / 32;
  int s0 = blockIdx.y * stepChunk;
  int s1 = min(stepsTot, s0 + stepChunk);
  int cg = tid & 31, kr8 = tid >> 5;
  int c0l = 4 * cg;
  bool fullC = (colBase + 128 <= Nc);

  f32x4 acc[18];
#pragma unroll
  for (int mt = 0; mt < 18; ++mt) {
    acc[mt][0] = 0.f; acc[mt][1] = 0.f; acc[mt][2] = 0.f; acc[mt][3] = 0.f;
  }

  auto stage = [&](int s, int buf) {
#pragma unroll
    for (int h = 0; h < 2; ++h) {
      int kp = kr8 + 8 * h;
      int kA = s * 32 + 2 * kp;
      int kB = kA + 1;
      float4 r0 = {0.f, 0.f, 0.f, 0.f}, r1 = {0.f, 0.f, 0.f, 0.f};
      int c0 = colBase + c0l;
      if (fullC) {
        if (kA < K) r0 = *(const float4*)(W + (size_t)kA * Nc + c0);
        if (kB < K) r1 = *(const float4*)(W + (size_t)kB * Nc + c0);
      } else {
        float rr0[4] = {0.f, 0.f, 0.f, 0.f}, rr1[4] = {0.f, 0.f, 0.f, 0.f};
#pragma unroll
        for (int e = 0; e < 4; ++e) {
          if (c0 + e < Nc) {
            if (kA < K) rr0[e] = W[(size_t)kA * Nc + c0 + e];
            if (kB < K) rr1[e] = W[(size_t)kB * Nc + c0 + e];
          }
        }
        r0.x = rr0[0]; r0.y = rr0[1]; r0.z = rr0[2]; r0.w = rr0[3];
        r1.x = rr1[0]; r1.y = rr1[1]; r1.z = rr1[2]; r1.w = rr1[3];
      }
      lds[buf][c0l + 0][kp] = ((unsigned int)f2bf(r1.x) << 16) | f2bf(r0.x);
      lds[buf][c0l + 1][kp] = ((unsigned int)f2bf(r1.y) << 16) | f2bf(r0.y);
      lds[buf][c0l + 2][kp] = ((unsigned int)f2bf(r1.z) << 16) | f2bf(r0.z);
      lds[buf][c0l + 3][kp] = ((unsigned int)f2bf(r1.w) << 16) | f2bf(r0.w);
    }
  };

  if (s0 < s1) stage(s0, 0);
  __syncthreads();

  const unsigned short* ap = At + ((size_t)(s0 * 4 + lo) * R3_ + lr) * 8;
  const size_t apStep = (size_t)4 * R3_ * 8;
  int lcol0 = w * 32 + lr;
  int lcol1 = w * 32 + 16 + lr;
  for (int s = s0; s < s1; ++s) {
    int buf = (s - s0) & 1;
    union { unsigned int u[4]; short8 s8; } b0, b1;
#pragma unroll
    for (int j = 0; j < 4; ++j) {
      b0.u[j] = lds[buf][lcol0][lo * 4 + j];
      b1.u[j] = lds[buf][lcol1][lo * 4 + j];
    }
#pragma unroll
    for (int mt = 0; mt < 9; ++mt) {
      short8 a = *(const short8*)(ap + (size_t)mt * 128);
      acc[mt] = __builtin_amdgcn_mfma_f32_16x16x32_bf16(a, b0.s8, acc[mt], 0, 0, 0);
      acc[9 + mt] = __builtin_amdgcn_mfma_f32_16x16x32_bf16(a, b1.s8, acc[9 + mt], 0, 0, 0);
    }
    if (s + 1 < s1) stage(s + 1, buf ^ 1);
    __syncthreads();
    ap += apStep;
  }

#pragma unroll
  for (int half = 0; half < 2; ++half) {
    int gcol = colBase + w * 32 + half * 16 + lr;
    if (gcol < Nc) {
#pragma unroll
      for (int mt = 0; mt < 9; ++mt) {
        int row = mt * 16 + lo * 4;
        float* pp = part + ((size_t)blockIdx.y * R3_ + row) * Nc + gcol;
        f32x4 a = acc[half * 9 + mt];
        pp[0] = a[0];
        pp[(size_t)Nc] = a[1];
        pp[2 * (size_t)Nc] = a[2];
        pp[3 * (size_t)Nc] = a[3];
      }
    }
  }
}

// ---------------------------------------------------------------------------
// Epilogues
// ---------------------------------------------------------------------------
__global__ void k_minmax(const float* __restrict__ alin, float* __restrict__ mmp) {
  int g = blockIdx.y;
  float mn = 3.4e38f, mx = -3.4e38f;
  for (int i = blockIdx.x * 256 + threadIdx.x; i < N_ * BT_; i += 64 * 256) {
    int n = i / BT_, r = i % BT_;
    float v = alin[(size_t)n * R3_ + g * BT_ + r];
    mn = fminf(mn, v); mx = fmaxf(mx, v);
  }
  __shared__ float rn[4], rx[4];
  for (int off = 32; off; off >>= 1) {
    mn = fminf(mn, __shfl_down(mn, off));
    mx = fmaxf(mx, __shfl_down(mx, off));
  }
  if ((threadIdx.x & 63) == 0) { rn[threadIdx.x >> 6] = mn; rx[threadIdx.x >> 6] = mx; }
  __syncthreads();
  if (threadIdx.x == 0) {
    mn = fminf(fminf(rn[0], rn[1]), fminf(rn[2], rn[3]));
    mx = fmaxf(fmaxf(rx[0], rx[1]), fmaxf(rx[2], rx[3]));
    mmp[(size_t)(g * 64 + blockIdx.x) * 2] = mn;
    mmp[(size_t)(g * 64 + blockIdx.x) * 2 + 1] = mx;
  }
}

__global__ void k_minmax2(float* __restrict__ ws) {
  int g = blockIdx.x;
  int i = threadIdx.x;
  float mn = ws[OFF_MMP + (size_t)(g * 64 + i) * 2];
  float mx = ws[OFF_MMP + (size_t)(g * 64 + i) * 2 + 1];
  for (int off = 32; off; off >>= 1) {
    mn = fminf(mn, __shfl_down(mn, off));
    mx = fmaxf(mx, __shfl_down(mx, off));
  }
  if (i == 0) {
    float denom = fmaxf(mx - mn, 1e-8f);
    float a = 1.f / denom;
    ws[OFF_AB + g * 2] = a;
    ws[OFF_AB + g * 2 + 1] = -mn * a;
  }
}

__global__ void k_colsum(const float* __restrict__ ltw, float* __restrict__ csp) {
  int e = blockIdx.x * 256 + threadIdx.x;
  int ks = blockIdx.y;
  if (e >= EA_) return;
  float s = 0.f;
  for (int n = ks * 125; n < (ks + 1) * 125; ++n) s += ltw[(size_t)n * EA_ + e];
  csp[(size_t)ks * EA_ + e] = s;
}
__global__ void k_colsum2(float* __restrict__ ws) {
  int e = blockIdx.x * 256 + threadIdx.x;
  if (e >= EA_) return;
  float s = 0.f;
  for (int ks = 0; ks < 16; ++ks) s += ws[OFF_CSP + (size_t)ks * EA_ + e];
  ws[OFF_CS + e] = s;
}

__global__ void k_epiLin(const float* __restrict__ part, const float* __restrict__ ltb,
                         float* __restrict__ ws, unsigned short* __restrict__ atq,
                         int ksplit) {
  int e = blockIdx.x * 256 + threadIdx.x;
  int row = blockIdx.y;
  if (e >= KP3) return;
  if (e >= EA_) { atq[aidx(row, e)] = 0; return; }
  float s = 0.f;
  for (int ks = 0; ks < ksplit; ++ks) s += part[((size_t)(ks * R3_ + row)) * EA_ + e];
  int g = row / BT_;
  float a = ws[OFF_AB + g * 2], bb = ws[OFF_AB + g * 2 + 1];
  float val = fmaf(a, s, fmaf(bb, ws[OFF_CS + e], ltb[e]));
  atq[aidx(row, e)] = f2bf(val);
}

__global__ void k_epiQkv(const float* __restrict__ part, const float* __restrict__ qkvb,
                         float* __restrict__ P, int ksplit) {
  int c = blockIdx.x * 256 + threadIdx.x;
  int row = blockIdx.y;
  if (c >= 3 * EA_) return;
  float s = 0.f;
  for (int ks = 0; ks < ksplit; ++ks) s += part[((size_t)(ks * R3_ + row)) * (3 * EA_) + c];
  P[(size_t)row * (3 * EA_) + c] = s + qkvb[c];
}

// attention: waves cover t in parallel (wave-local reductions, one barrier)
__global__ void k_attn(const float* __restrict__ P, unsigned short* __restrict__ atao) {
  int mha = blockIdx.y;
  int s_ = blockIdx.x / (B_ * H_);
  int rem = blockIdx.x % (B_ * H_);
  int b = rem / H_, h = rem % H_;
  const int pq[3] = {0, 1, 2}, pk[3] = {1, 2, 0}, pv[3] = {2, 0, 1};
  const float* qrow = P + ((size_t)(pq[mha] * BT_ + s_ * B_ + b)) * (3 * EA_) + h * HD_;
  __shared__ float sc[T_];
  int w = threadIdx.x >> 6, lane = threadIdx.x & 63;
  for (int t = w; t < T_; t += 4) {
    const float* krow = P + ((size_t)(pk[mha] * BT_ + t * B_ + b)) * (3 * EA_) + EA_ + h * HD_;
    float p = 0.f;
    for (int d = lane; d < HD_; d += 64) p = fmaf(qrow[d], krow[d], p);
    p = waveReduceSum(p);
    if (lane == 0) sc[t] = p * 0.031622776601683794f;
  }
  __syncthreads();
  float a[T_];
  float m = sc[0];
#pragma unroll
  for (int t = 1; t < T_; ++t) m = fmaxf(m, sc[t]);
  float sum = 0.f;
#pragma unroll
  for (int t = 0; t < T_; ++t) { a[t] = expf(sc[t] - m); sum += a[t]; }
  float inv = 1.f / sum;
#pragma unroll
  for (int t = 0; t < T_; ++t) a[t] *= inv;
  int orow = mha * BT_ + s_ * B_ + b;
  for (int d = threadIdx.x; d < HD_; d += 256) {
    float o = 0.f;
#pragma unroll
    for (int t = 0; t < T_; ++t)
      o = fmaf(a[t], P[((size_t)(pv[mha] * BT_ + t * B_ + b)) * (3 * EA_) + 2 * EA_ + h * HD_ + d], o);
    atao[aidx(orow, h * HD_ + d)] = f2bf(o);
  }
  if (h == 0 && threadIdx.x < 8) atao[aidx(orow, EA_ + threadIdx.x)] = 0;
}

__global__ void k_epiAO(const float* __restrict__ part, const float* __restrict__ aob,
                        unsigned short* __restrict__ atll, int ksplit) {
  int c = blockIdx.x * 256 + threadIdx.x;
  int row = blockIdx.y;
  if (c >= KP3) return;
  if (c >= EA_) { atll[aidx(row, c)] = 0; return; }
  float s = 0.f;
  for (int ks = 0; ks < ksplit; ++ks) s += part[((size_t)(ks * R3_ + row)) * EA_ + c];
  atll[aidx(row, c)] = f2bf(s + aob[c]);
}

__global__ void k_epiLL(const float* __restrict__ part, const float* __restrict__ llb,
                        float* __restrict__ o2p, int ksplit) {
  int n = blockIdx.x * 256 + threadIdx.x;
  int row = blockIdx.y;  // t*B+b
  if (n >= N_) return;
  float s = 0.f;
  for (int g = 0; g < 3; ++g)
    for (int ks = 0; ks < ksplit; ++ks)
      s += part[((size_t)(ks * R3_ + g * BT_ + row)) * N_ + n];
  int t = row / B_, b = row % B_;
  o2p[(size_t)b * (T_ * N_) + t * N_ + n] = BETA_ * (s + 3.f * llb[n]);
}

// ---------------------------------------------------------------------------
// Fused proj + p2 + out3 + f-normalization: one thread per (b,n) row.
// v1[t] = proj(out4), v2[t] = p2(o2p); dout = v1+v2; bf16 g1b/g2b rows.
// ---------------------------------------------------------------------------
__global__ void k_ppf(const float* __restrict__ out4, const float* __restrict__ pw,
                      const float* __restrict__ pb, const float* __restrict__ o2p,
                      const float* __restrict__ p2w, const float* __restrict__ p2b,
                      float* __restrict__ dout, unsigned short* __restrict__ g1b,
                      unsigned short* __restrict__ g2b) {
  int r = blockIdx.x * 64 + threadIdx.x;
  if (r >= B_ * N_) return;
  int b = r / N_, n = r % N_;
  // trunk projection
  float v1[T_];
#pragma unroll
  for (int t = 0; t < T_; ++t) v1[t] = pb[t];
  for (int t2 = 0; t2 < T_; ++t2) {
    const float* o = out4 + ((size_t)(b * T_ + t2) * N_ + n) * D_;
#pragma unroll
    for (int d = 0; d < D_; ++d) {
      float od = o[d];
      const float* pr = pw + (t2 * D_ + d) * T_;
#pragma unroll
      for (int t = 0; t < T_; ++t) v1[t] = fmaf(od, pr[t], v1[t]);
    }
  }
  // p2 (reads 12 consecutive elements of the flat [T,N] block)
  const float* src = o2p + (size_t)b * (T_ * N_) + (size_t)n * T_;
  float v2[T_];
#pragma unroll
  for (int t = 0; t < T_; ++t) v2[t] = p2b[t];
#pragma unroll
  for (int c = 0; c < T_; ++c) {
    float sc = src[c];
    const float* pr = p2w + c * T_;
#pragma unroll
    for (int t = 0; t < T_; ++t) v2[t] = fmaf(sc, pr[t], v2[t]);
  }
  // out3 + norms + bf16 rows
  float s1 = 0.f, s2 = 0.f;
#pragma unroll
  for (int t = 0; t < T_; ++t) {
    size_t idx = (size_t)b * T_ * N_ + (size_t)t * N_ + n;
    dout[idx] = v1[t] + v2[t];
    s1 = fmaf(v1[t], v1[t], s1);
    s2 = fmaf(v2[t], v2[t], s2);
  }
  float n1 = fmaxf(sqrtf(s1), 1e-12f), n2 = fmaxf(sqrtf(s2), 1e-12f);
  float i1 = 10.f / n1, i2 = 1.f / n2;
  unsigned short q[32], z[32];
#pragma unroll
  for (int t = 0; t < T_; ++t) { q[t] = f2bf(v1[t] * i1); z[t] = f2bf(v2[t] * i2); }
#pragma unroll
  for (int t = T_; t < 32; ++t) { q[t] = 0; z[t] = 0; }
  short8* qd = (short8*)(g1b + (size_t)r * 32);
  short8* zd = (short8*)(g2b + (size_t)r * 32);
#pragma unroll
  for (int c = 0; c < 4; ++c) {
    short8 pv, pz;
#pragma unroll
    for (int e = 0; e < 8; ++e) { pv[e] = (short)q[c * 8 + e]; pz[e] = (short)z[c * 8 + e]; }
    qd[c] = pv;
    zd[c] = pz;
  }
}

// MFMA logsumexp: per block 16 q-rows; 16 j-slices (4 waves x grid.y=4)
__global__ __launch_bounds__(256) void k_lsemf(const unsigned short* __restrict__ g1b,
                                               const unsigned short* __restrict__ g2b,
                                               float* __restrict__ psm,
                                               float* __restrict__ psd) {
  int lane = threadIdx.x & 63, w = threadIdx.x >> 6;
  int lr = lane & 15, lo = lane >> 4;
  int i0 = blockIdx.x * 16;
  int slice = blockIdx.y * 4 + w;     // 0..15
  short8 a = *(const short8*)(g1b + (size_t)(i0 + lr) * 32 + lo * 8);
  float sm[4] = {0.f, 0.f, 0.f, 0.f};
  float sd[4] = {0.f, 0.f, 0.f, 0.f};
  for (int t = slice; t < 500; t += 16) {
    int j0 = t * 16;
    short8 b = *(const short8*)(g2b + (size_t)(j0 + lr) * 32 + lo * 8);
    f32x4 acc = {0.f, 0.f, 0.f, 0.f};
    acc = __builtin_amdgcn_mfma_f32_16x16x32_bf16(a, b, acc, 0, 0, 0);
#pragma unroll
    for (int rg = 0; rg < 4; ++rg) {
      float s = acc[rg];
      sm[rg] += __expf(s);
      if (j0 + lr == i0 + lo * 4 + rg) sd[rg] = s;
    }
  }
#pragma unroll
  for (int off = 1; off < 16; off <<= 1) {
#pragma unroll
    for (int rg = 0; rg < 4; ++rg) {
      sm[rg] += __shfl_xor(sm[rg], off);
      sd[rg] += __shfl_xor(sd[rg], off);
    }
  }
  __shared__ float lsm[4][16], lsd[4][16];
  if (lr == 0) {
#pragma unroll
    for (int rg = 0; rg < 4; ++rg) {
      lsm[w][lo * 4 + rg] = sm[rg];
      lsd[w][lo * 4 + rg] = sd[rg];
    }
  }
  __syncthreads();
  if (threadIdx.x < 16) {
    float m = lsm[0][threadIdx.x] + lsm[1][threadIdx.x] + lsm[2][threadIdx.x] + lsm[3][threadIdx.x];
    float d = lsd[0][threadIdx.x] + lsd[1][threadIdx.x] + lsd[2][threadIdx.x] + lsd[3][threadIdx.x];
    psm[(size_t)blockIdx.y * 8000 + i0 + threadIdx.x] = m;
    psd[(size_t)blockIdx.y * 8000 + i0 + threadIdx.x] = d;
  }
}

// fused: combine j-splits + mean + final scalars
__global__ __launch_bounds__(1024) void k_lsefin(const float* __restrict__ psm,
                                                 const float* __restrict__ psd,
                                                 const float* __restrict__ ws,
                                                 float* __restrict__ dout) {
  float acc = 0.f;
  for (int r = threadIdx.x; r < B_ * N_; r += 1024) {
    float sm = psm[r] + psm[8000 + r] + psm[16000 + r] + psm[24000 + r];
    float sd = psd[r] + psd[8000 + r] + psd[16000 + r] + psd[24000 + r];
    acc += sd - logf(sm);
  }
  __shared__ float red[16];
  acc = waveReduceSum(acc);
  if ((threadIdx.x & 63) == 0) red[threadIdx.x >> 6] = acc;
  __syncthreads();
  if (threadIdx.x == 0) {
    float s = 0.f;
    for (int i = 0; i < 16; ++i) s += red[i];
    float closs = -s * (1.f / (B_ * N_));
    dout[BTN_] = ws[OFF_BAL];
    dout[BTN_ + 1] = CW_ * closs;
  }
}

// ---------------------------------------------------------------------------
extern "C" void kernel_launch(void* const* d_in, const int* in_sizes, int n_in,
                              void* d_out, int out_size, void* d_ws, size_t ws_size,
                              hipStream_t stream) {
  const float* x    = (const float*)d_in[0];
  const float* velo = (const float*)d_in[1];
  const float* adj  = (const float*)d_in[2];
  const float* lapd = (const float*)d_in[3];
  const float* laph = (const float*)d_in[4];
  const float* sw   = (const float*)d_in[5];
  const float* sb   = (const float*)d_in[6];
  const float* gw   = (const float*)d_in[7];
  const float* ew1  = (const float*)d_in[8];
  const float* eb1  = (const float*)d_in[9];
  const float* ew2  = (const float*)d_in[10];
  const float* eb2  = (const float*)d_in[11];
  const float* pw   = (const float*)d_in[12];
  const float* pb   = (const float*)d_in[13];
  const float* ltw  = (const float*)d_in[14];
  const float* ltb  = (const float*)d_in[15];
  const float* qkvw = (const float*)d_in[16];
  const float* qkvb = (const float*)d_in[17];
  const float* aow  = (const float*)d_in[18];
  const float* aob  = (const float*)d_in[19];
  const float* llw  = (const float*)d_in[20];
  const float* llb  = (const float*)d_in[21];
  const float* p2w  = (const float*)d_in[22];
  const float* p2b  = (const float*)d_in[23];
  float* ws = (float*)d_ws;
  float* dout = (float*)d_out;
  const float* v0 = velo;  // velo[0,0,:]
  float* part = ws + OFF_PART;
  unsigned short* atLin = (unsigned short*)(ws + OFF_AT_LIN);
  unsigned short* atQ   = (unsigned short*)(ws + OFF_AT_Q);
  unsigned short* atAO  = (unsigned short*)(ws + OFF_AT_AO);
  unsigned short* atLL  = (unsigned short*)(ws + OFF_AT_LL);
  unsigned short* g1b   = (unsigned short*)(ws + OFF_G1B);
  unsigned short* g2b   = (unsigned short*)(ws + OFF_G2B);
  dim3 b256(256);

  k_init<<<dim3(1), dim3(64), 0, stream>>>(ws);

  k_start<<<dim3((BTN_ * D_ + 255) / 256), b256, 0, stream>>>(x, sw, sb, ws + OFF_OUT4);

  for (int l = 0; l < L_; ++l) {
    k_feat<<<dim3(B_ * D_), b256, 0, stream>>>(ws + OFF_OUT4, ws + OFF_FEAT);
    k_gate<<<dim3(1), dim3(64), 0, stream>>>(ws + OFF_FEAT, gw, ws, l);
    k_expert<<<dim3((T_ * N_ + 255) / 256, B_), b256, 0, stream>>>(ws + OFF_OUT4, ew1, eb1, ew2, eb2, ws, l);
  }

  k_wavelet<<<dim3((BTN_ + 255) / 256), b256, 0, stream>>>(x, velo, ws + OFF_LOWT, ws + OFF_HVT);
  k_rowsum<<<dim3(2 * BT_), b256, 0, stream>>>(ws + OFF_LOWT, ws + OFF_HVT, ws);
  k_S<<<dim3(N_), b256, 0, stream>>>(adj, v0, ws + OFF_S);

  // fused r1/r2/r3 GEMMs (with in-line B stats) then stats reduce + epilogue
  k_rgemm3<<<dim3(8, RKS_, 9), b256, 0, stream>>>(ws + OFF_LOWT, ws + OFF_HVT, lapd, laph,
                                                  adj, v0, ws + OFF_S, part, ws + OFF_STP);
  k_stats2<<<dim3(3), b256, 0, stream>>>(ws + OFF_STP, ws + OFF_STAT);
  k_epiR3<<<dim3(8, 48, 3), b256, 0, stream>>>(part, ws, atLin);

  k_minmax<<<dim3(64, 3), b256, 0, stream>>>(ws + OFF_ALIN, ws + OFF_MMP);
  k_minmax2<<<dim3(3), dim3(64), 0, stream>>>(ws);
  k_colsum<<<dim3(12, 16), b256, 0, stream>>>(ltw, ws + OFF_CSP);
  k_colsum2<<<dim3(12), b256, 0, stream>>>(ws);

  // lin (MFMA, 64-col tiles): 16 splits x 4 steps (63 steps)
  k_mfmaW<<<dim3(47, 16), b256, 0, stream>>>(atLin, ltw, part, EA_, KP2, N_, 4);
  k_epiLin<<<dim3(12, 144), b256, 0, stream>>>(part, ltb, ws, atQ, 16);

  // qkv (MFMA, 128-col tiles): 10 splits x 10 steps (94 steps)
  k_mfmaWq<<<dim3(71, 10), b256, 0, stream>>>(atQ, qkvw, part, 3 * EA_, KP3, EA_, 10);
  k_epiQkv<<<dim3(36, 144), b256, 0, stream>>>(part, qkvb, ws + OFF_P, 10);

  // attention
  k_attn<<<dim3(T_ * B_ * H_, 3), b256, 0, stream>>>(ws + OFF_P, atAO);

  // attn-out (MFMA, 64-col tiles): 16 splits x 6 steps
  k_mfmaW<<<dim3(47, 16), b256, 0, stream>>>(atAO, aow, part, EA_, KP3, EA_, 6);
  k_epiAO<<<dim3(12, 144), b256, 0, stream>>>(part, aob, atLL, 16);

  // ll (MFMA, 64-col tiles): 20 splits x 5 steps
  k_mfmaW<<<dim3(32, 20), b256, 0, stream>>>(atLL, llw, part, N_, KP3, EA_, 5);
  k_epiLL<<<dim3(8, 48), b256, 0, stream>>>(part, llb, ws + OFF_O2P, 20);

  // fused proj + p2 + out3 + fnorm (writes dout body + bf16 g1b/g2b)
  k_ppf<<<dim3((B_ * N_ + 63) / 64), dim3(64), 0, stream>>>(ws + OFF_OUT4, pw, pb,
                                                            ws + OFF_O2P, p2w, p2b,
                                                            dout, g1b, g2b);

  // MFMA logsumexp; psm/psd partials live in `part`
  k_lsemf<<<dim3(500, 4), b256, 0, stream>>>(g1b, g2b, part, part + 32000);
  k_lsefin<<<dim3(1), dim3(1024), 0, stream>>>(part, part + 32000, ws, dout);
}